// Round 17
// baseline (384.321 us; speedup 1.0000x reference)
//
#include <hip/hip_runtime.h>
#include <hip/hip_bf16.h>

// ---------------------------------------------------------------------------
// TransformerBlock: LN1 -> QKV GEMM -> causal flash attn -> out-proj(+x) -> h
//                   LN2 -> FFN1(+gelu) -> FFN2(+h) -> out
// R20 = R19 + gemm_p8 for FFN1: faithful m201-style 8-phase 256x256 BK=64
//  kernel. Per K-tile: 4 phases, each {ds_read [8,4,8,4] b128; stage ONE
//  16KB K-half (2 gload_lds/thr); s_barrier; lgkmcnt(0); setprio(1); 16 MFMA;
//  setprio(0); s_barrier}; counted vmcnt(4) ONLY at tile boundaries (never 0
//  until tail). K-half regions free mid-tile (k0 dead after phase 2) ->
//  per-phase staging into the live dbuf without races (full hazard audit in
//  derivation). Stage schedule during tile T: [B-k1(T+1), A-k1(T+1),
//  A-k0(T+2), B-k0(T+2)]. 2 dbufs x {A-k0|A-k1|B-k0|B-k1} 16KB panels.
// R19-R15: attn combined sweep + Q hoist + setprio; prep merge; VT_FUSE.
// GEMMs: ring-3 counted-vmcnt 128x128 for QKV/out-proj/FFN2; FFN1 -> p8.
// ---------------------------------------------------------------------------

typedef float f32x4 __attribute__((ext_vector_type(4)));
typedef __bf16 bf16x8 __attribute__((ext_vector_type(8)));
typedef unsigned short u16;

#define MFMA16(a, b, c) __builtin_amdgcn_mfma_f32_16x16x32_bf16((a), (b), (c), 0, 0, 0)

#define GLL16(g, l)                                                            \
  __builtin_amdgcn_global_load_lds(                                            \
      (__attribute__((address_space(1))) void*)(g),                            \
      (__attribute__((address_space(3))) void*)(l), 16, 0, 0)

__device__ __forceinline__ u16 f2bf(float f) {
  union { float f; unsigned int u; } x; x.f = f;
  unsigned int r = x.u + 0x7fffu + ((x.u >> 16) & 1u);
  return (u16)(r >> 16);
}

// ---- prep: blocks [0,12288) = weight transposes, [12288,20480) = LN1 -------
__global__ __launch_bounds__(256) void prep_kernel(
    const float* __restrict__ w_qkv, u16* __restrict__ wqkvT,
    const float* __restrict__ w_out, u16* __restrict__ woutT,
    const float* __restrict__ w1,    u16* __restrict__ w1T,
    const float* __restrict__ w2,    u16* __restrict__ w2T,
    const float* __restrict__ x, const float* __restrict__ g,
    const float* __restrict__ b, u16* __restrict__ y)
{
  __shared__ u16 tile[32][33];
  __shared__ float red[8];
  int bid = blockIdx.x;
  int t = threadIdx.x;
  if (bid < 12288) {
    const float* W; u16* Wt; int K, N, nb, base;
    if (bid < 3072)      { W = w_qkv; Wt = wqkvT; K = 1024; N = 3072; nb = 96;  base = 0; }
    else if (bid < 4096) { W = w_out; Wt = woutT; K = 1024; N = 1024; nb = 32;  base = 3072; }
    else if (bid < 8192) { W = w1;    Wt = w1T;   K = 1024; N = 4096; nb = 128; base = 4096; }
    else                 { W = w2;    Wt = w2T;   K = 4096; N = 1024; nb = 32;  base = 8192; }
    int idx = bid - base;
    int n0 = (idx % nb) * 32, k0 = (idx / nb) * 32;
    int tr = t >> 5, tc = t & 31;
#pragma unroll
    for (int i = 0; i < 4; ++i) {
      int k = k0 + tr + i * 8;
      tile[tc][tr + i * 8] = f2bf(W[(size_t)k * N + n0 + tc]);
    }
    __syncthreads();
#pragma unroll
    for (int i = 0; i < 4; ++i) {
      int n = n0 + tr + i * 8;
      Wt[(size_t)n * K + k0 + tc] = tile[tr + i * 8][tc];
    }
  } else {
    int row = bid - 12288;
    const float4* xr = (const float4*)(x + (size_t)row * 1024);
    float4 v = xr[t];
    float s  = v.x + v.y + v.z + v.w;
    float ss = v.x*v.x + v.y*v.y + v.z*v.z + v.w*v.w;
#pragma unroll
    for (int off = 1; off < 64; off <<= 1) {
      s  += __shfl_xor(s, off);
      ss += __shfl_xor(ss, off);
    }
    int w = t >> 6;
    if ((t & 63) == 0) { red[w*2] = s; red[w*2+1] = ss; }
    __syncthreads();
    s  = red[0] + red[2] + red[4] + red[6];
    ss = red[1] + red[3] + red[5] + red[7];
    float mu  = s * (1.0f / 1024.0f);
    float var = ss * (1.0f / 1024.0f) - mu * mu;
    float rs  = rsqrtf(var + 1e-5f);
    float4 gg = ((const float4*)g)[t];
    float4 bb = ((const float4*)b)[t];
    ushort4 o;
    o.x = f2bf((v.x - mu) * rs * gg.x + bb.x);
    o.y = f2bf((v.y - mu) * rs * gg.y + bb.y);
    o.z = f2bf((v.z - mu) * rs * gg.z + bb.z);
    o.w = f2bf((v.w - mu) * rs * gg.w + bb.w);
    ((ushort4*)y)[(size_t)row * 256 + t] = o;
  }
}

// ---------------- LayerNorm: fp32 in -> bf16 out, one row per block ---------
__global__ __launch_bounds__(256) void ln_kernel(
    const float* __restrict__ x, const float* __restrict__ g,
    const float* __restrict__ b, u16* __restrict__ y)
{
  int row = blockIdx.x;
  int t = threadIdx.x;
  const float4* xr = (const float4*)(x + (size_t)row * 1024);
  float4 v = xr[t];
  float s  = v.x + v.y + v.z + v.w;
  float ss = v.x*v.x + v.y*v.y + v.z*v.z + v.w*v.w;
#pragma unroll
  for (int off = 1; off < 64; off <<= 1) {
    s  += __shfl_xor(s, off);
    ss += __shfl_xor(ss, off);
  }
  __shared__ float red[8];
  int w = t >> 6;
  if ((t & 63) == 0) { red[w*2] = s; red[w*2+1] = ss; }
  __syncthreads();
  s  = red[0] + red[2] + red[4] + red[6];
  ss = red[1] + red[3] + red[5] + red[7];
  float mu  = s * (1.0f / 1024.0f);
  float var = ss * (1.0f / 1024.0f) - mu * mu;
  float rs  = rsqrtf(var + 1e-5f);
  float4 gg = ((const float4*)g)[t];
  float4 bb = ((const float4*)b)[t];
  ushort4 o;
  o.x = f2bf((v.x - mu) * rs * gg.x + bb.x);
  o.y = f2bf((v.y - mu) * rs * gg.y + bb.y);
  o.z = f2bf((v.z - mu) * rs * gg.z + bb.z);
  o.w = f2bf((v.w - mu) * rs * gg.w + bb.w);
  ((ushort4*)y)[(size_t)row * 256 + t] = o;
}

// ---------------- GEMM 256x256 BK=64 8-phase (m201-derived) -----------------
// dbuf layout (64KB): [A-k0 16K][A-k1 16K][B-k0 16K][B-k1 16K]; K-half panel
// = 256 rows x 32 cols bf16 (64B rows, R7-verified unit swizzle).
// Wave grid 2(M)x4(N); wave output 128x64 = 8m x 4n frags; acc[8][4].
template<int GELU, int OUT_BF16>
__global__ __launch_bounds__(512, 2) void gemm_p8(
    const u16* __restrict__ A, const u16* __restrict__ Bt,
    const float* __restrict__ bias, void* __restrict__ Cout,
    int M, int N, int K)
{
  __shared__ u16 lds[2][32768];   // 64KB per dbuf
  const int nbn = N >> 8;
  int nwg = gridDim.x, wg = blockIdx.x;
  if ((nwg & 7) == 0) wg = (wg & 7) * (nwg >> 3) + (wg >> 3);
  const int bm = wg / nbn, bn = wg % nbn;
  const int tid = threadIdx.x;
  const int w = tid >> 6, l = tid & 63;
  const int lh = l & 15, lg = l >> 4;
  const int wr = w >> 2, wc = w & 3;
  const size_t Kb = (size_t)K * 2;
  const char* Ab = (const char*)A + (size_t)(bm * 256) * Kb;
  const char* Bb = (const char*)Bt + (size_t)(bn * 256) * Kb;

  // staging a 16KB K-half: thread stages units {tid, tid+512}; row = tid>>2
  // (+128), dst unit = tid&3, src unit pre-swizzled ^ ((row>>1)&3).
  const int swst = ((tid ^ (tid >> 3)) & 3) << 4;
  const size_t stR = (size_t)(tid >> 2) * Kb + swst;

#define SHALF(base, T, ks, dst)                                                \
  do {                                                                         \
    const char* s_ = (base) + stR + (size_t)(T) * 128 + (ks) * 64;             \
    GLL16(s_, (dst) + tid * 16);                                               \
    GLL16(s_ + 128 * Kb, (dst) + tid * 16 + 8192);                             \
  } while (0)
#define SA(T, ks, sel) SHALF(Ab, T, ks, (char*)lds[sel] + (ks) * 16384)
#define SB(T, ks, sel) SHALF(Bb, T, ks, (char*)lds[sel] + 32768 + (ks) * 16384)

  // frag reads: row = base16 + lh -> swizzle constant ((lg ^ (lh>>1))&3)
  const int swo = ((lg ^ (lh >> 1)) & 3) << 4;
  const int offA = (wr * 128 + lh) * 64 + swo;          // +mh*4096 +f*1024 +ks*16384
  const int offB = 32768 + (wc * 64 + lh) * 64 + swo;   // +n*1024 +ks*16384

  f32x4 acc[8][4] = {};
  const int nkt = K >> 6;
  // prologue: k0(0), k1(0), k0(1); vmcnt(4) -> tile 0 fully resident
  SA(0, 0, 0); SB(0, 0, 0); SB(0, 1, 0); SA(0, 1, 0); SA(1, 0, 1); SB(1, 0, 1);
  asm volatile("s_waitcnt vmcnt(4)" ::: "memory");
  __builtin_amdgcn_s_barrier();
  __builtin_amdgcn_sched_barrier(0);

#pragma unroll 1
  for (int T = 0; T < nkt; ++T) {
    const int cur = T & 1;
    const char* buf = (const char*)lds[cur];
    bf16x8 bk[4], af[4];
    // ---- phase 1: (mh0, ks0); stage B-k1(T+1) -> dbuf cur^1 ----
#pragma unroll
    for (int n = 0; n < 4; ++n) bk[n] = *(const bf16x8*)(buf + offB + n * 1024);
#pragma unroll
    for (int f = 0; f < 4; ++f) af[f] = *(const bf16x8*)(buf + offA + f * 1024);
    if (T + 1 < nkt) SB(T + 1, 1, cur ^ 1);
    __builtin_amdgcn_s_barrier();
    asm volatile("s_waitcnt lgkmcnt(0)" ::: "memory");
    __builtin_amdgcn_sched_barrier(0);
    __builtin_amdgcn_s_setprio(1);
#pragma unroll
    for (int f = 0; f < 4; ++f)
#pragma unroll
      for (int n = 0; n < 4; ++n) acc[f][n] = MFMA16(af[f], bk[n], acc[f][n]);
    __builtin_amdgcn_s_setprio(0);
    __builtin_amdgcn_s_barrier();
    // ---- phase 2: (mh1, ks0); stage A-k1(T+1); reuse bk ----
#pragma unroll
    for (int f = 0; f < 4; ++f)
      af[f] = *(const bf16x8*)(buf + offA + 4096 + f * 1024);
    if (T + 1 < nkt) SA(T + 1, 1, cur ^ 1);
    __builtin_amdgcn_s_barrier();
    asm volatile("s_waitcnt lgkmcnt(0)" ::: "memory");
    __builtin_amdgcn_sched_barrier(0);
    __builtin_amdgcn_s_setprio(1);
#pragma unroll
    for (int f = 0; f < 4; ++f)
#pragma unroll
      for (int n = 0; n < 4; ++n) acc[4 + f][n] = MFMA16(af[f], bk[n], acc[4 + f][n]);
    __builtin_amdgcn_s_setprio(0);
    __builtin_amdgcn_s_barrier();
    // ---- phase 3: (mh0, ks1); stage A-k0(T+2) -> dbuf cur (k0 dead) ----
#pragma unroll
    for (int n = 0; n < 4; ++n)
      bk[n] = *(const bf16x8*)(buf + offB + 16384 + n * 1024);
#pragma unroll
    for (int f = 0; f < 4; ++f)
      af[f] = *(const bf16x8*)(buf + offA + 16384 + f * 1024);
    if (T + 2 < nkt) SA(T + 2, 0, cur);
    __builtin_amdgcn_s_barrier();
    asm volatile("s_waitcnt lgkmcnt(0)" ::: "memory");
    __builtin_amdgcn_sched_barrier(0);
    __builtin_amdgcn_s_setprio(1);
#pragma unroll
    for (int f = 0; f < 4; ++f)
#pragma unroll
      for (int n = 0; n < 4; ++n) acc[f][n] = MFMA16(af[f], bk[n], acc[f][n]);
    __builtin_amdgcn_s_setprio(0);
    __builtin_amdgcn_s_barrier();
    // ---- phase 4: (mh1, ks1); stage B-k0(T+2); reuse bk ----
#pragma unroll
    for (int f = 0; f < 4; ++f)
      af[f] = *(const bf16x8*)(buf + offA + 16384 + 4096 + f * 1024);
    if (T + 2 < nkt) SB(T + 2, 0, cur);
    __builtin_amdgcn_s_barrier();
    asm volatile("s_waitcnt lgkmcnt(0)" ::: "memory");
    __builtin_amdgcn_sched_barrier(0);
    __builtin_amdgcn_s_setprio(1);
#pragma unroll
    for (int f = 0; f < 4; ++f)
#pragma unroll
      for (int n = 0; n < 4; ++n) acc[4 + f][n] = MFMA16(af[f], bk[n], acc[4 + f][n]);
    __builtin_amdgcn_s_setprio(0);
    // ---- tile boundary: counted vmcnt (never 0 until tail) ----
    if (T < nkt - 1) {
      __builtin_amdgcn_sched_barrier(0);
      if (T < nkt - 2) asm volatile("s_waitcnt vmcnt(4)" ::: "memory");
      else             asm volatile("s_waitcnt vmcnt(0)" ::: "memory");
      __builtin_amdgcn_s_barrier();
      __builtin_amdgcn_sched_barrier(0);
    }
  }
#undef SA
#undef SB
#undef SHALF

#pragma unroll
  for (int m = 0; m < 8; ++m) {
    int row0 = bm * 256 + wr * 128 + m * 16 + lg * 4;
#pragma unroll
    for (int n = 0; n < 4; ++n) {
      int col = bn * 256 + wc * 64 + n * 16 + lh;
      float bv = bias[col];
#pragma unroll
      for (int r = 0; r < 4; ++r) {
        int row = row0 + r;
        float v = acc[m][n][r] + bv;
        if (GELU) v = 0.5f * v * (1.0f + erff(v * 0.70710678118f));
        if (OUT_BF16) ((u16*)Cout)[(size_t)row * N + col] = f2bf(v);
        else ((float*)Cout)[(size_t)row * N + col] = v;
      }
    }
  }
  (void)M;
}

// --------------------- GEMM 128x128 ring-3 (R5, verified) -------------------
template<int GELU, int HAS_RES, int OUT_BF16, int VT_FUSE>
__global__ __launch_bounds__(256, 2) void gemm_ring3(
    const u16* __restrict__ A, const u16* __restrict__ Bt,
    const float* __restrict__ bias, const float* __restrict__ res,
    void* __restrict__ Cout, u16* __restrict__ vt, int M, int N, int K)
{
  __shared__ u16 lA[3][128 * 32];
  __shared__ u16 lB[3][128 * 32];
  const int nbn = N >> 7;
  int nwg = gridDim.x;
  int wg = blockIdx.x;
  if ((nwg & 7) == 0) wg = (wg & 7) * (nwg >> 3) + (wg >> 3);
  int bm = wg / nbn, bn = wg % nbn;
  int tid = threadIdx.x;
  int w = tid >> 6, l = tid & 63;
  int lh = l & 15, lg = l >> 4;
  int wr = w >> 1, wc = w & 1;
  const size_t Kb = (size_t)K * 2;
  const char* Ab = (const char*)A + (size_t)(bm * 128) * Kb;
  const char* Bb = (const char*)Bt + (size_t)(bn * 128) * Kb;

  int c0 = w * 64 + l;
  int r0 = c0 >> 2, sw0 = ((c0 ^ (c0 >> 3)) & 3) << 4;
  int c1 = (4 + w) * 64 + l;
  int r1 = c1 >> 2, sw1 = ((c1 ^ (c1 >> 3)) & 3) << 4;

#define GSTAGE(sel, kt)                                                        \
  do {                                                                         \
    GLL16(Ab + (size_t)r0 * Kb + (size_t)(kt) * 64 + sw0,                      \
          (char*)lA[sel] + w * 1024);                                          \
    GLL16(Bb + (size_t)r0 * Kb + (size_t)(kt) * 64 + sw0,                      \
          (char*)lB[sel] + w * 1024);                                          \
    GLL16(Ab + (size_t)r1 * Kb + (size_t)(kt) * 64 + sw1,                      \
          (char*)lA[sel] + (4 + w) * 1024);                                    \
    GLL16(Bb + (size_t)r1 * Kb + (size_t)(kt) * 64 + sw1,                      \
          (char*)lB[sel] + (4 + w) * 1024);                                    \
  } while (0)

  const int swo = ((lg ^ (lh >> 1)) & 3) << 4;
  const int offA = (wr * 64 + lh) * 64 + swo;
  const int offB = (wc * 64 + lh) * 64 + swo;

  f32x4 acc[4][4] = {};
  const int nkt = K >> 5;
  GSTAGE(0, 0);
  GSTAGE(1, 1);
  asm volatile("s_waitcnt vmcnt(4)" ::: "memory");   // tile 0 resident
  __builtin_amdgcn_s_barrier();
  __builtin_amdgcn_sched_barrier(0);

  int cur = 0, s2 = 2;
#pragma unroll 1
  for (int t = 0; t < nkt; ++t) {
    const char* bufA = (const char*)lA[cur];
    const char* bufB = (const char*)lB[cur];
    bf16x8 af[4], bfr[4];
#pragma unroll
    for (int m = 0; m < 4; ++m)
      af[m] = *(const bf16x8*)(bufA + offA + m * 1024);
#pragma unroll
    for (int n = 0; n < 4; ++n)
      bfr[n] = *(const bf16x8*)(bufB + offB + n * 1024);
    if (t + 2 < nkt) GSTAGE(s2, t + 2);   // async, lands 2 steps ahead
    __builtin_amdgcn_s_setprio(1);
#pragma unroll
    for (int m = 0; m < 4; ++m)
#pragma unroll
      for (int n = 0; n < 4; ++n)
        acc[m][n] = MFMA16(af[m], bfr[n], acc[m][n]);
    __builtin_amdgcn_s_setprio(0);
    if (t < nkt - 1) {
      __builtin_amdgcn_sched_barrier(0);
      if (t < nkt - 2) asm volatile("s_waitcnt vmcnt(4)" ::: "memory");
      else             asm volatile("s_waitcnt vmcnt(0)" ::: "memory");
      __builtin_amdgcn_s_barrier();      // tile t+1 resident for all waves
      __builtin_amdgcn_sched_barrier(0);
    }
    cur = (cur == 2) ? 0 : cur + 1;
    s2  = (s2 == 2) ? 0 : s2 + 1;
  }
#undef GSTAGE

#pragma unroll
  for (int m = 0; m < 4; ++m) {
    int row0 = bm * 128 + wr * 64 + m * 16 + lg * 4;
#pragma unroll
    for (int n = 0; n < 4; ++n) {
      int col = bn * 128 + wc * 64 + n * 16 + lh;
      float bv = bias[col];
      if (VT_FUSE && col >= 2048) {
        // V block: write transposed to vtb[b,h,d,l]. Wave-uniform branch.
        int hh = (col - 2048) >> 6, dd = (col - 2048) & 63;
        int bb = row0 >> 11, ll = row0 & 2047;   // rows 4-aligned, same b
        ushort4 pk;
        pk.x = f2bf(acc[m][n][0] + bv);
        pk.y = f2bf(acc[m][n][1] + bv);
        pk.z = f2bf(acc[m][n][2] + bv);
        pk.w = f2bf(acc[m][n][3] + bv);
        *(ushort4*)(vt + ((size_t)((bb * 16 + hh) * 64 + dd)) * 2048 + ll) = pk;
      } else {
#pragma unroll
        for (int r = 0; r < 4; ++r) {
          int row = row0 + r;
          float v = acc[m][n][r] + bv;
          if (GELU) v = 0.5f * v * (1.0f + erff(v * 0.70710678118f));
          if (HAS_RES) v += res[(size_t)row * N + col];
          if (OUT_BF16) ((u16*)Cout)[(size_t)row * N + col] = f2bf(v);
          else ((float*)Cout)[(size_t)row * N + col] = v;
        }
      }
    }
  }
  (void)M;
}

// --------------------------- causal flash attention -------------------------
// R18: combined sweep; R19: Q frags hoisted; R17: setprio clusters.
__global__ __launch_bounds__(256, 4) void attn_kernel(
    const u16* __restrict__ qkv, const u16* __restrict__ vt,
    u16* __restrict__ out)
{
  __shared__ u16 Ks[2][4096];
  __shared__ u16 Vs[2][4096];
  __shared__ u16 Ps[4][1024];

  const float C = 0.18033688011f;  // 0.125 * log2(e)

  int bid = blockIdx.x;
  int pi = bid >> 6, bh = bid & 63;
  int b = bh >> 4, h = bh & 15;
  int tid = threadIdx.x;
  int w = tid >> 6, l = tid & 63;
  int lh = l & 15, lg = l >> 4;
  int lh7 = lh & 7;

  const char* kg = (const char*)qkv + (size_t)(b * 2048) * 6144 + 2048 + h * 128;
  const char* vg = (const char*)vt + (size_t)((b * 16 + h) * 64) * 4096;
  char* pbw = (char*)Ps[w] + lh * 128;

  const int qbA = pi, qbB = 31 - pi;
  const int q0A = qbA * 64 + w * 16, q0B = qbB * 64 + w * 16;
  const u16* qApt = qkv + ((size_t)(b * 2048) + q0A) * 3072 + h * 64;
  const u16* qBpt = qkv + ((size_t)(b * 2048) + q0B) * 3072 + h * 64;
  bf16x8 aqA0 = *(const bf16x8*)(qApt + (size_t)lh * 3072 + lg * 8);
  bf16x8 aqA1 = *(const bf16x8*)(qApt + (size_t)lh * 3072 + 32 + lg * 8);
  bf16x8 aqB0 = *(const bf16x8*)(qBpt + (size_t)lh * 3072 + lg * 8);
  bf16x8 aqB1 = *(const bf16x8*)(qBpt + (size_t)lh * 3072 + 32 + lg * 8);

  f32x4 oA[4] = {}, oB[4] = {};
  float mA = -1e30f, lsA = 0.f, mB = -1e30f, lsB = 0.f;
  const int nt = qbB + 1;   // 32 - pi

#pragma unroll
  for (int i = 0; i < 2; ++i) {
    int u = tid + i * 256;
    int row = u >> 3, uc = u & 7, sw = uc ^ (row & 7);
    GLL16(kg + (size_t)row * 6144 + sw * 16,
          (char*)Ks[0] + (size_t)(i * 256 + w * 64) * 16);
    GLL16(vg + (size_t)row * 4096 + sw * 16,
          (char*)Vs[0] + (size_t)(i * 256 + w * 64) * 16);
  }

#pragma unroll 1
  for (int kt = 0; kt < nt; ++kt) {
    int cur = kt & 1;
    __syncthreads();
    if (kt + 1 < nt) {
      int nxt = cur ^ 1;
      size_t kofs = (size_t)(kt + 1) * 64;
#pragma unroll
      for (int i = 0; i < 2; ++i) {
        int u = tid + i * 256;
        int row = u >> 3, uc = u & 7, sw = uc ^ (row & 7);
        GLL16(kg + (kofs + row) * 6144 + sw * 16,
              (char*)Ks[nxt] + (size_t)(i * 256 + w * 64) * 16);
        GLL16(vg + (size_t)row * 4096 + kofs * 2 + sw * 16,
              (char*)Vs[nxt] + (size_t)(i * 256 + w * 64) * 16);
      }
    }
    const char* kbuf = (const char*)Ks[cur];
    const char* vbuf = (const char*)Vs[cur];

    // ================= q-tile B (always active) =================
    {
      f32x4 s[4];
      __builtin_amdgcn_s_setprio(1);
#pragma unroll
      for (int kb = 0; kb < 4; ++kb) {
        int row = kb * 16 + lh;
        const char* rp = kbuf + row * 128;
        bf16x8 a0 = *(const bf16x8*)(rp + ((lg ^ lh7) << 4));
        bf16x8 a1 = *(const bf16x8*)(rp + (((4 + lg) ^ lh7) << 4));
        f32x4 z = {0.f, 0.f, 0.f, 0.f};
        z = MFMA16(a0, aqB0, z);
        z = MFMA16(a1, aqB1, z);
        s[kb] = z;
      }
      __builtin_amdgcn_s_setprio(0);
      if (kt == qbB) {
        int qin = w * 16 + lh;
#pragma unroll
        for (int kb = 0; kb < 4; ++kb)
#pragma unroll
          for (int r = 0; r < 4; ++r)
            if (kb * 16 + lg * 4 + r > qin) s[kb][r] = -1e30f;
      }
      float tm = fmaxf(fmaxf(s[0][0], s[0][1]), fmaxf(s[0][2], s[0][3]));
#pragma unroll
      for (int kb = 1; kb < 4; ++kb)
        tm = fmaxf(tm, fmaxf(fmaxf(s[kb][0], s[kb][1]), fmaxf(s[kb][2], s[kb][3])));
      tm = fmaxf(tm, __shfl_xor(tm, 16));
      tm = fmaxf(tm, __shfl_xor(tm, 32));
      if (__any(tm > mB + 64.0f)) {
        float nm = fmaxf(mB, tm);
        float f = __builtin_amdgcn_exp2f((mB - nm) * C);
        mB = nm; lsB *= f;
#pragma unroll
        for (int db = 0; db < 4; ++db)
#pragma unroll
          for (int r = 0; r < 4; ++r) oB[db][r] *= f;
      }
      float mc = mB * C;
      float ps = 0.f;
#pragma unroll
      for (int kb = 0; kb < 4; ++kb)
#pragma unroll
        for (int r = 0; r < 4; ++r) {
          float p = __builtin_amdgcn_exp2f(fmaf(s[kb][r], C, -mc));
          s[kb][r] = p;
          ps += p;
        }
      ps += __shfl_xor(ps, 16);
      ps += __shfl_xor(ps, 32);
      lsB += ps;
#pragma unroll
      for (int kb = 0; kb < 4; ++kb) {
        unsigned lo, hi;
        asm("v_cvt_pk_bf16_f32 %0, %1, %2" : "=v"(lo) : "v"(s[kb][0]), "v"(s[kb][1]));
        asm("v_cvt_pk_bf16_f32 %0, %1, %2" : "=v"(hi) : "v"(s[kb][2]), "v"(s[kb][3]));
        int unit = kb * 2 + (lg >> 1);
        uint2 val; val.x = lo; val.y = hi;
        *(uint2*)(pbw + ((unit ^ lh7) << 4) + ((lg & 1) << 3)) = val;
      }
      bf16x8 pa0 = *(const bf16x8*)(pbw + ((lg ^ lh7) << 4));
      bf16x8 pa1 = *(const bf16x8*)(pbw + (((4 + lg) ^ lh7) << 4));
      __builtin_amdgcn_s_setprio(1);
#pragma unroll
      for (int db = 0; db < 4; ++db) {
        int row = db * 16 + lh;
        const char* rp = vbuf + row * 128;
        bf16x8 v0 = *(const bf16x8*)(rp + ((lg ^ lh7) << 4));
        bf16x8 v1 = *(const bf16x8*)(rp + (((4 + lg) ^ lh7) << 4));
        oB[db] = MFMA16(v0, pa0, oB[db]);
        oB[db] = MFMA16(v1, pa1, oB[db]);
      }
      __builtin_amdgcn_s_setprio(0);
    }

    // ================= q-tile A (active while kt <= qbA) =================
    if (kt <= qbA) {   // block-uniform branch
      f32x4 s[4];
      __builtin_amdgcn_s_setprio(1);
#pragma unroll
      for (int kb = 0; kb < 4; ++kb) {
        int row = kb * 16 + lh;
        const char* rp = kbuf + row * 128;
        bf16x8 a0 = *(const bf16x8*)(rp + ((lg ^ lh7) << 4));
        bf16x8 a1 = *(const bf16x8*)(rp + (((4 + lg) ^ lh7) << 4));
        f32x4 z = {0.f, 0.f, 0.f, 0.f};
        z = MFMA16(a0, aqA0, z);
        z = MFMA16(a1, aqA1, z);
        s[kb] = z;
      }
      __builtin_amdgcn_s_setprio(0);
      if (kt == qbA) {
        int qin = w * 16 + lh;
#pragma unroll
        for (int kb = 0; kb < 4; ++kb)
#pragma unroll
          for (int r = 0; r < 4; ++r)
            if (kb * 16 + lg * 4 + r > qin) s[kb][r] = -1e30f;
      }
      float tm = fmaxf(fmaxf(s[0][0], s[0][1]), fmaxf(s[0][2], s[0][3]));
#pragma unroll
      for (int kb = 1; kb < 4; ++kb)
        tm = fmaxf(tm, fmaxf(fmaxf(s[kb][0], s[kb][1]), fmaxf(s[kb][2], s[kb][3])));
      tm = fmaxf(tm, __shfl_xor(tm, 16));
      tm = fmaxf(tm, __shfl_xor(tm, 32));
      if (__any(tm > mA + 64.0f)) {
        float nm = fmaxf(mA, tm);
        float f = __builtin_amdgcn_exp2f((mA - nm) * C);
        mA = nm; lsA *= f;
#pragma unroll
        for (int db = 0; db < 4; ++db)
#pragma unroll
          for (int r = 0; r < 4; ++r) oA[db][r] *= f;
      }
      float mc = mA * C;
      float ps = 0.f;
#pragma unroll
      for (int kb = 0; kb < 4; ++kb)
#pragma unroll
        for (int r = 0; r < 4; ++r) {
          float p = __builtin_amdgcn_exp2f(fmaf(s[kb][r], C, -mc));
          s[kb][r] = p;
          ps += p;
        }
      ps += __shfl_xor(ps, 16);
      ps += __shfl_xor(ps, 32);
      lsA += ps;
#pragma unroll
      for (int kb = 0; kb < 4; ++kb) {
        unsigned lo, hi;
        asm("v_cvt_pk_bf16_f32 %0, %1, %2" : "=v"(lo) : "v"(s[kb][0]), "v"(s[kb][1]));
        asm("v_cvt_pk_bf16_f32 %0, %1, %2" : "=v"(hi) : "v"(s[kb][2]), "v"(s[kb][3]));
        int unit = kb * 2 + (lg >> 1);
        uint2 val; val.x = lo; val.y = hi;
        *(uint2*)(pbw + ((unit ^ lh7) << 4) + ((lg & 1) << 3)) = val;
      }
      bf16x8 pa0 = *(const bf16x8*)(pbw + ((lg ^ lh7) << 4));
      bf16x8 pa1 = *(const bf16x8*)(pbw + (((4 + lg) ^ lh7) << 4));
      __builtin_amdgcn_s_setprio(1);
#pragma unroll
      for (int db = 0; db < 4; ++db) {
        int row = db * 16 + lh;
        const char* rp = vbuf + row * 128;
        bf16x8 v0 = *(const bf16x8*)(rp + ((lg ^ lh7) << 4));
        bf16x8 v1 = *(const bf16x8*)(rp + (((4 + lg) ^ lh7) << 4));
        oA[db] = MFMA16(v0, pa0, oA[db]);
        oA[db] = MFMA16(v1, pa1, oA[db]);
      }
      __builtin_amdgcn_s_setprio(0);
    }
  }

  {
    float rinv = 1.0f / lsB;
    u16* ob = out + ((size_t)(b * 2048) + q0B + lh) * 1024 + h * 64;
#pragma unroll
    for (int db = 0; db < 4; ++db) {
      ushort4 pk;
      pk.x = f2bf(oB[db][0] * rinv);
      pk.y = f2bf(oB[db][1] * rinv);
      pk.z = f2bf(oB[db][2] * rinv);
      pk.w = f2bf(oB[db][3] * rinv);
      *(ushort4*)(ob + db * 16 + lg * 4) = pk;
    }
  }
  {
    float rinv = 1.0f / lsA;
    u16* ob = out + ((size_t)(b * 2048) + q0A + lh) * 1024 + h * 64;
#pragma unroll
    for (int db = 0; db < 4; ++db) {
      ushort4 pk;
      pk.x = f2bf(oA[db][0] * rinv);
      pk.y = f2bf(oA[db][1] * rinv);
      pk.z = f2bf(oA[db][2] * rinv);
      pk.w = f2bf(oA[db][3] * rinv);
      *(ushort4*)(ob + db * 16 + lg * 4) = pk;
    }
  }
}

// ---------------------------------------------------------------------------
extern "C" void kernel_launch(void* const* d_in, const int* in_sizes, int n_in,
                              void* d_out, int out_size, void* d_ws, size_t ws_size,
                              hipStream_t stream) {
  const float* x     = (const float*)d_in[0];
  const float* ln1_g = (const float*)d_in[1];
  const float* ln1_b = (const float*)d_in[2];
  const float* w_qkv = (const float*)d_in[3];
  const float* b_qkv = (const float*)d_in[4];
  const float* w_out = (const float*)d_in[5];
  const float* b_out = (const float*)d_in[6];
  const float* ln2_g = (const float*)d_in[7];
  const float* ln2_b = (const float*)d_in[8];
  const float* w1    = (const float*)d_in[9];
  const float* b1    = (const float*)d_in[10];
  const float* w2    = (const float*)d_in[11];
  const float* b2    = (const float*)d_in[12];

  char* ws = (char*)d_ws;
  // liveness-aliased layout, 142.6 MB total
  u16* wqkvT = (u16*)(ws + 0);          // 6.29 MB
  u16* woutT = (u16*)(ws + 6291456);    // 2.10 MB
  u16* w1T   = (u16*)(ws + 8388608);    // 8.39 MB
  u16* w2T   = (u16*)(ws + 16777216);   // 8.39 MB
  u16* qkv   = (u16*)(ws + 25165824);   // 50.3 MB  [b,l,3,h,d] (V region unused)
  u16* ffn1  = (u16*)(ws + 25165824);   // 67.1 MB  (aliases qkv+vt, both dead)
  u16* vtb   = (u16*)(ws + 75497472);   // 16.8 MB  [b,h,d,l] (written by QKV epi)
  u16* lnb   = (u16*)(ws + 92274688);   // 16.8 MB  (ln1 out / attn out / ln2 out)
  u16* attn  = lnb;
  float* h   = (float*)(ws + 125829120);// 33.6 MB

  // prep: 4 weight transposes (12288 blocks) + LN1 (8192 blocks), one launch
  prep_kernel<<<20480, 256, 0, stream>>>(w_qkv, wqkvT, w_out, woutT,
                                         w1, w1T, w2, w2T,
                                         x, ln1_g, ln1_b, lnb);
  // QKV: K=1024 -> ring-3 + fused V-transpose
  gemm_ring3<0, 0, 1, 1><<<1536, 256, 0, stream>>>(lnb, wqkvT, b_qkv, nullptr, qkv, vtb, 8192, 3072, 1024);
  attn_kernel<<<1024, 256, 0, stream>>>(qkv, vtb, attn);
  // out-proj: K=1024 -> ring-3
  gemm_ring3<0, 1, 0, 0><<<512, 256, 0, stream>>>(attn, woutT, b_out, x, h, nullptr, 8192, 1024, 1024);
  ln_kernel<<<8192, 256, 0, stream>>>(h, ln2_g, ln2_b, lnb);
  // FFN1: M=8192 N=4096 K=1024 -> 8-phase 256x256 (512 wg, 2 CU rounds)
  gemm_p8<1, 1><<<512, 512, 0, stream>>>(lnb, w1T, b1, ffn1, 8192, 4096, 1024);
  // FFN2: K=4096 -> ring-3 counted vmcnt (long K-loop amortizes pipeline)
  gemm_ring3<0, 1, 0, 0><<<512, 256, 0, stream>>>(ffn1, w2T, b2, h, (float*)d_out, nullptr, 8192, 1024, 4096);
}

// Round 18
// 366.927 us; speedup vs baseline: 1.0474x; 1.0474x over previous
//
#include <hip/hip_runtime.h>
#include <hip/hip_bf16.h>

// ---------------------------------------------------------------------------
// TransformerBlock: LN1 -> QKV GEMM -> causal flash attn -> out-proj(+x) -> h
//                   LN2 -> FFN1(+gelu) -> FFN2(+h) -> out
// R21 = R19 (session best, 366.1us). Five 8-phase/256^2 attempts (R4/R6/R8/
//  R10/R20) all landed ~168-178us at 1 blk/CU — quadrant permanently closed;
//  FFN1 stays on the 2-buf 128^2 kernel (135us = its L2/L3-supply floor).
// R19: attn tile-A Q-frag hoist. R18: combined sweep (q-tiles {pi,31-pi}
//  share one K/V staging pass). R17: setprio around attn MFMA clusters.
// R16: prep merge (4 wt + LN1 in one launch). R15: VT_FUSE (V written
//  transposed in QKV epilogue; vt_kernel deleted).
// GEMMs (R12 routing): ring-3 counted-vmcnt 128x128 for QKV/out-proj/FFN2;
//  2-buf syncthreads-drain 128x128 for FFN1. Zero-conflict XOR unit swizzle
//  + XCD chunking (bn-major falsified R13).
// ---------------------------------------------------------------------------

typedef float f32x4 __attribute__((ext_vector_type(4)));
typedef __bf16 bf16x8 __attribute__((ext_vector_type(8)));
typedef unsigned short u16;

#define MFMA16(a, b, c) __builtin_amdgcn_mfma_f32_16x16x32_bf16((a), (b), (c), 0, 0, 0)

#define GLL16(g, l)                                                            \
  __builtin_amdgcn_global_load_lds(                                            \
      (__attribute__((address_space(1))) void*)(g),                            \
      (__attribute__((address_space(3))) void*)(l), 16, 0, 0)

__device__ __forceinline__ u16 f2bf(float f) {
  union { float f; unsigned int u; } x; x.f = f;
  unsigned int r = x.u + 0x7fffu + ((x.u >> 16) & 1u);
  return (u16)(r >> 16);
}

// ---- prep: blocks [0,12288) = weight transposes, [12288,20480) = LN1 -------
__global__ __launch_bounds__(256) void prep_kernel(
    const float* __restrict__ w_qkv, u16* __restrict__ wqkvT,
    const float* __restrict__ w_out, u16* __restrict__ woutT,
    const float* __restrict__ w1,    u16* __restrict__ w1T,
    const float* __restrict__ w2,    u16* __restrict__ w2T,
    const float* __restrict__ x, const float* __restrict__ g,
    const float* __restrict__ b, u16* __restrict__ y)
{
  __shared__ u16 tile[32][33];
  __shared__ float red[8];
  int bid = blockIdx.x;
  int t = threadIdx.x;
  if (bid < 12288) {
    const float* W; u16* Wt; int K, N, nb, base;
    if (bid < 3072)      { W = w_qkv; Wt = wqkvT; K = 1024; N = 3072; nb = 96;  base = 0; }
    else if (bid < 4096) { W = w_out; Wt = woutT; K = 1024; N = 1024; nb = 32;  base = 3072; }
    else if (bid < 8192) { W = w1;    Wt = w1T;   K = 1024; N = 4096; nb = 128; base = 4096; }
    else                 { W = w2;    Wt = w2T;   K = 4096; N = 1024; nb = 32;  base = 8192; }
    int idx = bid - base;
    int n0 = (idx % nb) * 32, k0 = (idx / nb) * 32;
    int tr = t >> 5, tc = t & 31;
#pragma unroll
    for (int i = 0; i < 4; ++i) {
      int k = k0 + tr + i * 8;
      tile[tc][tr + i * 8] = f2bf(W[(size_t)k * N + n0 + tc]);
    }
    __syncthreads();
#pragma unroll
    for (int i = 0; i < 4; ++i) {
      int n = n0 + tr + i * 8;
      Wt[(size_t)n * K + k0 + tc] = tile[tr + i * 8][tc];
    }
  } else {
    int row = bid - 12288;
    const float4* xr = (const float4*)(x + (size_t)row * 1024);
    float4 v = xr[t];
    float s  = v.x + v.y + v.z + v.w;
    float ss = v.x*v.x + v.y*v.y + v.z*v.z + v.w*v.w;
#pragma unroll
    for (int off = 1; off < 64; off <<= 1) {
      s  += __shfl_xor(s, off);
      ss += __shfl_xor(ss, off);
    }
    int w = t >> 6;
    if ((t & 63) == 0) { red[w*2] = s; red[w*2+1] = ss; }
    __syncthreads();
    s  = red[0] + red[2] + red[4] + red[6];
    ss = red[1] + red[3] + red[5] + red[7];
    float mu  = s * (1.0f / 1024.0f);
    float var = ss * (1.0f / 1024.0f) - mu * mu;
    float rs  = rsqrtf(var + 1e-5f);
    float4 gg = ((const float4*)g)[t];
    float4 bb = ((const float4*)b)[t];
    ushort4 o;
    o.x = f2bf((v.x - mu) * rs * gg.x + bb.x);
    o.y = f2bf((v.y - mu) * rs * gg.y + bb.y);
    o.z = f2bf((v.z - mu) * rs * gg.z + bb.z);
    o.w = f2bf((v.w - mu) * rs * gg.w + bb.w);
    ((ushort4*)y)[(size_t)row * 256 + t] = o;
  }
}

// ---------------- LayerNorm: fp32 in -> bf16 out, one row per block ---------
__global__ __launch_bounds__(256) void ln_kernel(
    const float* __restrict__ x, const float* __restrict__ g,
    const float* __restrict__ b, u16* __restrict__ y)
{
  int row = blockIdx.x;
  int t = threadIdx.x;
  const float4* xr = (const float4*)(x + (size_t)row * 1024);
  float4 v = xr[t];
  float s  = v.x + v.y + v.z + v.w;
  float ss = v.x*v.x + v.y*v.y + v.z*v.z + v.w*v.w;
#pragma unroll
  for (int off = 1; off < 64; off <<= 1) {
    s  += __shfl_xor(s, off);
    ss += __shfl_xor(ss, off);
  }
  __shared__ float red[8];
  int w = t >> 6;
  if ((t & 63) == 0) { red[w*2] = s; red[w*2+1] = ss; }
  __syncthreads();
  s  = red[0] + red[2] + red[4] + red[6];
  ss = red[1] + red[3] + red[5] + red[7];
  float mu  = s * (1.0f / 1024.0f);
  float var = ss * (1.0f / 1024.0f) - mu * mu;
  float rs  = rsqrtf(var + 1e-5f);
  float4 gg = ((const float4*)g)[t];
  float4 bb = ((const float4*)b)[t];
  ushort4 o;
  o.x = f2bf((v.x - mu) * rs * gg.x + bb.x);
  o.y = f2bf((v.y - mu) * rs * gg.y + bb.y);
  o.z = f2bf((v.z - mu) * rs * gg.z + bb.z);
  o.w = f2bf((v.w - mu) * rs * gg.w + bb.w);
  ((ushort4*)y)[(size_t)row * 256 + t] = o;
}

// ------------------------- GEMM 128x128 2-buf (R7, verified) ----------------
template<int GELU, int HAS_RES, int OUT_BF16>
__global__ __launch_bounds__(256, 2) void gemm_kernel(
    const u16* __restrict__ A, const u16* __restrict__ Bt,
    const float* __restrict__ bias, const float* __restrict__ res,
    void* __restrict__ Cout, int M, int N, int K)
{
  __shared__ u16 lA[2][128 * 32];
  __shared__ u16 lB[2][128 * 32];
  const int nbn = N >> 7;
  int nwg = gridDim.x;
  int wg = blockIdx.x;
  if ((nwg & 7) == 0) wg = (wg & 7) * (nwg >> 3) + (wg >> 3);
  int bm = wg / nbn, bn = wg % nbn;
  int tid = threadIdx.x;
  int w = tid >> 6, l = tid & 63;
  int lh = l & 15, lg = l >> 4;
  int wr = w >> 1, wc = w & 1;
  const size_t Kb = (size_t)K * 2;
  const char* Ab = (const char*)A + (size_t)(bm * 128) * Kb;
  const char* Bb = (const char*)Bt + (size_t)(bn * 128) * Kb;

  int c0 = w * 64 + l;
  int r0 = c0 >> 2, sw0 = ((c0 ^ (c0 >> 3)) & 3) << 4;
  int c1 = (4 + w) * 64 + l;
  int r1 = c1 >> 2, sw1 = ((c1 ^ (c1 >> 3)) & 3) << 4;

#define GSTAGE(sel, kt)                                                        \
  do {                                                                         \
    GLL16(Ab + (size_t)r0 * Kb + (size_t)(kt) * 64 + sw0,                      \
          (char*)lA[sel] + w * 1024);                                          \
    GLL16(Bb + (size_t)r0 * Kb + (size_t)(kt) * 64 + sw0,                      \
          (char*)lB[sel] + w * 1024);                                          \
    GLL16(Ab + (size_t)r1 * Kb + (size_t)(kt) * 64 + sw1,                      \
          (char*)lA[sel] + (4 + w) * 1024);                                    \
    GLL16(Bb + (size_t)r1 * Kb + (size_t)(kt) * 64 + sw1,                      \
          (char*)lB[sel] + (4 + w) * 1024);                                    \
  } while (0)

  const int swo = ((lg ^ (lh >> 1)) & 3) << 4;
  const int offA = (wr * 64 + lh) * 64 + swo;
  const int offB = (wc * 64 + lh) * 64 + swo;

  f32x4 acc[4][4] = {};
  const int nkt = K >> 5;
  GSTAGE(0, 0);
  __syncthreads();
  int cur = 0;
#pragma unroll 1
  for (int kt = 0; kt < nkt; ++kt) {
    if (kt + 1 < nkt) GSTAGE(cur ^ 1, kt + 1);
    const char* bufA = (const char*)lA[cur];
    const char* bufB = (const char*)lB[cur];
    bf16x8 af[4], bfr[4];
#pragma unroll
    for (int m = 0; m < 4; ++m)
      af[m] = *(const bf16x8*)(bufA + offA + m * 1024);
#pragma unroll
    for (int n = 0; n < 4; ++n)
      bfr[n] = *(const bf16x8*)(bufB + offB + n * 1024);
#pragma unroll
    for (int m = 0; m < 4; ++m)
#pragma unroll
      for (int n = 0; n < 4; ++n)
        acc[m][n] = MFMA16(af[m], bfr[n], acc[m][n]);
    __syncthreads();
    cur ^= 1;
  }
#undef GSTAGE

#pragma unroll
  for (int m = 0; m < 4; ++m) {
    int row0 = bm * 128 + wr * 64 + m * 16 + lg * 4;
#pragma unroll
    for (int n = 0; n < 4; ++n) {
      int col = bn * 128 + wc * 64 + n * 16 + lh;
      float bv = bias[col];
#pragma unroll
      for (int r = 0; r < 4; ++r) {
        int row = row0 + r;
        float v = acc[m][n][r] + bv;
        if (GELU) v = 0.5f * v * (1.0f + erff(v * 0.70710678118f));
        if (HAS_RES) v += res[(size_t)row * N + col];
        if (OUT_BF16) ((u16*)Cout)[(size_t)row * N + col] = f2bf(v);
        else ((float*)Cout)[(size_t)row * N + col] = v;
      }
    }
  }
  (void)M;
}

// --------------------- GEMM 128x128 ring-3 (R5, verified) -------------------
template<int GELU, int HAS_RES, int OUT_BF16, int VT_FUSE>
__global__ __launch_bounds__(256, 2) void gemm_ring3(
    const u16* __restrict__ A, const u16* __restrict__ Bt,
    const float* __restrict__ bias, const float* __restrict__ res,
    void* __restrict__ Cout, u16* __restrict__ vt, int M, int N, int K)
{
  __shared__ u16 lA[3][128 * 32];
  __shared__ u16 lB[3][128 * 32];
  const int nbn = N >> 7;
  int nwg = gridDim.x;
  int wg = blockIdx.x;
  if ((nwg & 7) == 0) wg = (wg & 7) * (nwg >> 3) + (wg >> 3);
  int bm = wg / nbn, bn = wg % nbn;
  int tid = threadIdx.x;
  int w = tid >> 6, l = tid & 63;
  int lh = l & 15, lg = l >> 4;
  int wr = w >> 1, wc = w & 1;
  const size_t Kb = (size_t)K * 2;
  const char* Ab = (const char*)A + (size_t)(bm * 128) * Kb;
  const char* Bb = (const char*)Bt + (size_t)(bn * 128) * Kb;

  int c0 = w * 64 + l;
  int r0 = c0 >> 2, sw0 = ((c0 ^ (c0 >> 3)) & 3) << 4;
  int c1 = (4 + w) * 64 + l;
  int r1 = c1 >> 2, sw1 = ((c1 ^ (c1 >> 3)) & 3) << 4;

#define GSTAGE(sel, kt)                                                        \
  do {                                                                         \
    GLL16(Ab + (size_t)r0 * Kb + (size_t)(kt) * 64 + sw0,                      \
          (char*)lA[sel] + w * 1024);                                          \
    GLL16(Bb + (size_t)r0 * Kb + (size_t)(kt) * 64 + sw0,                      \
          (char*)lB[sel] + w * 1024);                                          \
    GLL16(Ab + (size_t)r1 * Kb + (size_t)(kt) * 64 + sw1,                      \
          (char*)lA[sel] + (4 + w) * 1024);                                    \
    GLL16(Bb + (size_t)r1 * Kb + (size_t)(kt) * 64 + sw1,                      \
          (char*)lB[sel] + (4 + w) * 1024);                                    \
  } while (0)

  const int swo = ((lg ^ (lh >> 1)) & 3) << 4;
  const int offA = (wr * 64 + lh) * 64 + swo;
  const int offB = (wc * 64 + lh) * 64 + swo;

  f32x4 acc[4][4] = {};
  const int nkt = K >> 5;
  GSTAGE(0, 0);
  GSTAGE(1, 1);
  asm volatile("s_waitcnt vmcnt(4)" ::: "memory");   // tile 0 resident
  __builtin_amdgcn_s_barrier();
  __builtin_amdgcn_sched_barrier(0);

  int cur = 0, s2 = 2;
#pragma unroll 1
  for (int t = 0; t < nkt; ++t) {
    const char* bufA = (const char*)lA[cur];
    const char* bufB = (const char*)lB[cur];
    bf16x8 af[4], bfr[4];
#pragma unroll
    for (int m = 0; m < 4; ++m)
      af[m] = *(const bf16x8*)(bufA + offA + m * 1024);
#pragma unroll
    for (int n = 0; n < 4; ++n)
      bfr[n] = *(const bf16x8*)(bufB + offB + n * 1024);
    if (t + 2 < nkt) GSTAGE(s2, t + 2);   // async, lands 2 steps ahead
    __builtin_amdgcn_s_setprio(1);
#pragma unroll
    for (int m = 0; m < 4; ++m)
#pragma unroll
      for (int n = 0; n < 4; ++n)
        acc[m][n] = MFMA16(af[m], bfr[n], acc[m][n]);
    __builtin_amdgcn_s_setprio(0);
    if (t < nkt - 1) {
      __builtin_amdgcn_sched_barrier(0);
      if (t < nkt - 2) asm volatile("s_waitcnt vmcnt(4)" ::: "memory");
      else             asm volatile("s_waitcnt vmcnt(0)" ::: "memory");
      __builtin_amdgcn_s_barrier();      // tile t+1 resident for all waves
      __builtin_amdgcn_sched_barrier(0);
    }
    cur = (cur == 2) ? 0 : cur + 1;
    s2  = (s2 == 2) ? 0 : s2 + 1;
  }
#undef GSTAGE

#pragma unroll
  for (int m = 0; m < 4; ++m) {
    int row0 = bm * 128 + wr * 64 + m * 16 + lg * 4;
#pragma unroll
    for (int n = 0; n < 4; ++n) {
      int col = bn * 128 + wc * 64 + n * 16 + lh;
      float bv = bias[col];
      if (VT_FUSE && col >= 2048) {
        // V block: write transposed to vtb[b,h,d,l]. Wave-uniform branch.
        int hh = (col - 2048) >> 6, dd = (col - 2048) & 63;
        int bb = row0 >> 11, ll = row0 & 2047;   // rows 4-aligned, same b
        ushort4 pk;
        pk.x = f2bf(acc[m][n][0] + bv);
        pk.y = f2bf(acc[m][n][1] + bv);
        pk.z = f2bf(acc[m][n][2] + bv);
        pk.w = f2bf(acc[m][n][3] + bv);
        *(ushort4*)(vt + ((size_t)((bb * 16 + hh) * 64 + dd)) * 2048 + ll) = pk;
      } else {
#pragma unroll
        for (int r = 0; r < 4; ++r) {
          int row = row0 + r;
          float v = acc[m][n][r] + bv;
          if (GELU) v = 0.5f * v * (1.0f + erff(v * 0.70710678118f));
          if (HAS_RES) v += res[(size_t)row * N + col];
          if (OUT_BF16) ((u16*)Cout)[(size_t)row * N + col] = f2bf(v);
          else ((float*)Cout)[(size_t)row * N + col] = v;
        }
      }
    }
  }
  (void)M;
}

// --------------------------- causal flash attention -------------------------
// R18: combined sweep — q-tiles A=pi and B=31-pi share one K/V staging pass
// (kt=0..31-pi; A active while kt<=pi). R19: A's Q frags hoisted to registers
// (loop-invariant). R17: setprio around MFMA clusters.
__global__ __launch_bounds__(256, 4) void attn_kernel(
    const u16* __restrict__ qkv, const u16* __restrict__ vt,
    u16* __restrict__ out)
{
  __shared__ u16 Ks[2][4096];
  __shared__ u16 Vs[2][4096];
  __shared__ u16 Ps[4][1024];

  const float C = 0.18033688011f;  // 0.125 * log2(e)

  int bid = blockIdx.x;
  int pi = bid >> 6, bh = bid & 63;
  int b = bh >> 4, h = bh & 15;
  int tid = threadIdx.x;
  int w = tid >> 6, l = tid & 63;
  int lh = l & 15, lg = l >> 4;
  int lh7 = lh & 7;

  const char* kg = (const char*)qkv + (size_t)(b * 2048) * 6144 + 2048 + h * 128;
  const char* vg = (const char*)vt + (size_t)((b * 16 + h) * 64) * 4096;
  char* pbw = (char*)Ps[w] + lh * 128;

  const int qbA = pi, qbB = 31 - pi;
  const int q0A = qbA * 64 + w * 16, q0B = qbB * 64 + w * 16;
  const u16* qApt = qkv + ((size_t)(b * 2048) + q0A) * 3072 + h * 64;
  const u16* qBpt = qkv + ((size_t)(b * 2048) + q0B) * 3072 + h * 64;
  bf16x8 aqA0 = *(const bf16x8*)(qApt + (size_t)lh * 3072 + lg * 8);
  bf16x8 aqA1 = *(const bf16x8*)(qApt + (size_t)lh * 3072 + 32 + lg * 8);
  bf16x8 aqB0 = *(const bf16x8*)(qBpt + (size_t)lh * 3072 + lg * 8);
  bf16x8 aqB1 = *(const bf16x8*)(qBpt + (size_t)lh * 3072 + 32 + lg * 8);

  f32x4 oA[4] = {}, oB[4] = {};
  float mA = -1e30f, lsA = 0.f, mB = -1e30f, lsB = 0.f;
  const int nt = qbB + 1;   // 32 - pi

#pragma unroll
  for (int i = 0; i < 2; ++i) {
    int u = tid + i * 256;
    int row = u >> 3, uc = u & 7, sw = uc ^ (row & 7);
    GLL16(kg + (size_t)row * 6144 + sw * 16,
          (char*)Ks[0] + (size_t)(i * 256 + w * 64) * 16);
    GLL16(vg + (size_t)row * 4096 + sw * 16,
          (char*)Vs[0] + (size_t)(i * 256 + w * 64) * 16);
  }

#pragma unroll 1
  for (int kt = 0; kt < nt; ++kt) {
    int cur = kt & 1;
    __syncthreads();
    if (kt + 1 < nt) {
      int nxt = cur ^ 1;
      size_t kofs = (size_t)(kt + 1) * 64;
#pragma unroll
      for (int i = 0; i < 2; ++i) {
        int u = tid + i * 256;
        int row = u >> 3, uc = u & 7, sw = uc ^ (row & 7);
        GLL16(kg + (kofs + row) * 6144 + sw * 16,
              (char*)Ks[nxt] + (size_t)(i * 256 + w * 64) * 16);
        GLL16(vg + (size_t)row * 4096 + kofs * 2 + sw * 16,
              (char*)Vs[nxt] + (size_t)(i * 256 + w * 64) * 16);
      }
    }
    const char* kbuf = (const char*)Ks[cur];
    const char* vbuf = (const char*)Vs[cur];

    // ================= q-tile B (always active) =================
    {
      f32x4 s[4];
      __builtin_amdgcn_s_setprio(1);
#pragma unroll
      for (int kb = 0; kb < 4; ++kb) {
        int row = kb * 16 + lh;
        const char* rp = kbuf + row * 128;
        bf16x8 a0 = *(const bf16x8*)(rp + ((lg ^ lh7) << 4));
        bf16x8 a1 = *(const bf16x8*)(rp + (((4 + lg) ^ lh7) << 4));
        f32x4 z = {0.f, 0.f, 0.f, 0.f};
        z = MFMA16(a0, aqB0, z);
        z = MFMA16(a1, aqB1, z);
        s[kb] = z;
      }
      __builtin_amdgcn_s_setprio(0);
      if (kt == qbB) {
        int qin = w * 16 + lh;
#pragma unroll
        for (int kb = 0; kb < 4; ++kb)
#pragma unroll
          for (int r = 0; r < 4; ++r)
            if (kb * 16 + lg * 4 + r > qin) s[kb][r] = -1e30f;
      }
      float tm = fmaxf(fmaxf(s[0][0], s[0][1]), fmaxf(s[0][2], s[0][3]));
#pragma unroll
      for (int kb = 1; kb < 4; ++kb)
        tm = fmaxf(tm, fmaxf(fmaxf(s[kb][0], s[kb][1]), fmaxf(s[kb][2], s[kb][3])));
      tm = fmaxf(tm, __shfl_xor(tm, 16));
      tm = fmaxf(tm, __shfl_xor(tm, 32));
      if (__any(tm > mB + 64.0f)) {
        float nm = fmaxf(mB, tm);
        float f = __builtin_amdgcn_exp2f((mB - nm) * C);
        mB = nm; lsB *= f;
#pragma unroll
        for (int db = 0; db < 4; ++db)
#pragma unroll
          for (int r = 0; r < 4; ++r) oB[db][r] *= f;
      }
      float mc = mB * C;
      float ps = 0.f;
#pragma unroll
      for (int kb = 0; kb < 4; ++kb)
#pragma unroll
        for (int r = 0; r < 4; ++r) {
          float p = __builtin_amdgcn_exp2f(fmaf(s[kb][r], C, -mc));
          s[kb][r] = p;
          ps += p;
        }
      ps += __shfl_xor(ps, 16);
      ps += __shfl_xor(ps, 32);
      lsB += ps;
#pragma unroll
      for (int kb = 0; kb < 4; ++kb) {
        unsigned lo, hi;
        asm("v_cvt_pk_bf16_f32 %0, %1, %2" : "=v"(lo) : "v"(s[kb][0]), "v"(s[kb][1]));
        asm("v_cvt_pk_bf16_f32 %0, %1, %2" : "=v"(hi) : "v"(s[kb][2]), "v"(s[kb][3]));
        int unit = kb * 2 + (lg >> 1);
        uint2 val; val.x = lo; val.y = hi;
        *(uint2*)(pbw + ((unit ^ lh7) << 4) + ((lg & 1) << 3)) = val;
      }
      bf16x8 pa0 = *(const bf16x8*)(pbw + ((lg ^ lh7) << 4));
      bf16x8 pa1 = *(const bf16x8*)(pbw + (((4 + lg) ^ lh7) << 4));
      __builtin_amdgcn_s_setprio(1);
#pragma unroll
      for (int db = 0; db < 4; ++db) {
        int row = db * 16 + lh;
        const char* rp = vbuf + row * 128;
        bf16x8 v0 = *(const bf16x8*)(rp + ((lg ^ lh7) << 4));
        bf16x8 v1 = *(const bf16x8*)(rp + (((4 + lg) ^ lh7) << 4));
        oB[db] = MFMA16(v0, pa0, oB[db]);
        oB[db] = MFMA16(v1, pa1, oB[db]);
      }
      __builtin_amdgcn_s_setprio(0);
    }

    // ================= q-tile A (active while kt <= qbA) =================
    if (kt <= qbA) {   // block-uniform branch
      f32x4 s[4];
      __builtin_amdgcn_s_setprio(1);
#pragma unroll
      for (int kb = 0; kb < 4; ++kb) {
        int row = kb * 16 + lh;
        const char* rp = kbuf + row * 128;
        bf16x8 a0 = *(const bf16x8*)(rp + ((lg ^ lh7) << 4));
        bf16x8 a1 = *(const bf16x8*)(rp + (((4 + lg) ^ lh7) << 4));
        f32x4 z = {0.f, 0.f, 0.f, 0.f};
        z = MFMA16(a0, aqA0, z);
        z = MFMA16(a1, aqA1, z);
        s[kb] = z;
      }
      __builtin_amdgcn_s_setprio(0);
      if (kt == qbA) {
        int qin = w * 16 + lh;
#pragma unroll
        for (int kb = 0; kb < 4; ++kb)
#pragma unroll
          for (int r = 0; r < 4; ++r)
            if (kb * 16 + lg * 4 + r > qin) s[kb][r] = -1e30f;
      }
      float tm = fmaxf(fmaxf(s[0][0], s[0][1]), fmaxf(s[0][2], s[0][3]));
#pragma unroll
      for (int kb = 1; kb < 4; ++kb)
        tm = fmaxf(tm, fmaxf(fmaxf(s[kb][0], s[kb][1]), fmaxf(s[kb][2], s[kb][3])));
      tm = fmaxf(tm, __shfl_xor(tm, 16));
      tm = fmaxf(tm, __shfl_xor(tm, 32));
      if (__any(tm > mA + 64.0f)) {
        float nm = fmaxf(mA, tm);
        float f = __builtin_amdgcn_exp2f((mA - nm) * C);
        mA = nm; lsA *= f;
#pragma unroll
        for (int db = 0; db < 4; ++db)
#pragma unroll
          for (int r = 0; r < 4; ++r) oA[db][r] *= f;
      }
      float mc = mA * C;
      float ps = 0.f;
#pragma unroll
      for (int kb = 0; kb < 4; ++kb)
#pragma unroll
        for (int r = 0; r < 4; ++r) {
          float p = __builtin_amdgcn_exp2f(fmaf(s[kb][r], C, -mc));
          s[kb][r] = p;
          ps += p;
        }
      ps += __shfl_xor(ps, 16);
      ps += __shfl_xor(ps, 32);
      lsA += ps;
#pragma unroll
      for (int kb = 0; kb < 4; ++kb) {
        unsigned lo, hi;
        asm("v_cvt_pk_bf16_f32 %0, %1, %2" : "=v"(lo) : "v"(s[kb][0]), "v"(s[kb][1]));
        asm("v_cvt_pk_bf16_f32 %0, %1, %2" : "=v"(hi) : "v"(s[kb][2]), "v"(s[kb][3]));
        int unit = kb * 2 + (lg >> 1);
        uint2 val; val.x = lo; val.y = hi;
        *(uint2*)(pbw + ((unit ^ lh7) << 4) + ((lg & 1) << 3)) = val;
      }
      bf16x8 pa0 = *(const bf16x8*)(pbw + ((lg ^ lh7) << 4));
      bf16x8 pa1 = *(const bf16x8*)(pbw + (((4 + lg) ^ lh7) << 4));
      __builtin_amdgcn_s_setprio(1);
#pragma unroll
      for (int db = 0; db < 4; ++db) {
        int row = db * 16 + lh;
        const char* rp = vbuf + row * 128;
        bf16x8 v0 = *(const bf16x8*)(rp + ((lg ^ lh7) << 4));
        bf16x8 v1 = *(const bf16x8*)(rp + (((4 + lg) ^ lh7) << 4));
        oA[db] = MFMA16(v0, pa0, oA[db]);
        oA[db] = MFMA16(v1, pa1, oA[db]);
      }
      __builtin_amdgcn_s_setprio(0);
    }
  }

  {
    float rinv = 1.0f / lsB;
    u16* ob = out + ((size_t)(b * 2048) + q0B + lh) * 1024 + h * 64;
#pragma unroll
    for (int db = 0; db < 4; ++db) {
      ushort4 pk;
      pk.x = f2bf(oB[db][0] * rinv);
      pk.y = f2bf(oB[db][1] * rinv);
      pk.z = f2bf(oB[db][2] * rinv);
      pk.w = f2bf(oB[db][3] * rinv);
      *(ushort4*)(ob + db * 16 + lg * 4) = pk;
    }
  }
  {
    float rinv = 1.0f / lsA;
    u16* ob = out + ((size_t)(b * 2048) + q0A + lh) * 1024 + h * 64;
#pragma unroll
    for (int db = 0; db < 4; ++db) {
      ushort4 pk;
      pk.x = f2bf(oA[db][0] * rinv);
      pk.y = f2bf(oA[db][1] * rinv);
      pk.z = f2bf(oA[db][2] * rinv);
      pk.w = f2bf(oA[db][3] * rinv);
      *(ushort4*)(ob + db * 16 + lg * 4) = pk;
    }
  }
}

// ---------------------------------------------------------------------------
extern "C" void kernel_launch(void* const* d_in, const int* in_sizes, int n_in,
                              void* d_out, int out_size, void* d_ws, size_t ws_size,
                              hipStream_t stream) {
  const float* x     = (const float*)d_in[0];
  const float* ln1_g = (const float*)d_in[1];
  const float* ln1_b = (const float*)d_in[2];
  const float* w_qkv = (const float*)d_in[3];
  const float* b_qkv = (const float*)d_in[4];
  const float* w_out = (const float*)d_in[5];
  const float* b_out = (const float*)d_in[6];
  const float* ln2_g = (const float*)d_in[7];
  const float* ln2_b = (const float*)d_in[8];
  const float* w1    = (const float*)d_in[9];
  const float* b1    = (const float*)d_in[10];
  const float* w2    = (const float*)d_in[11];
  const float* b2    = (const float*)d_in[12];

  char* ws = (char*)d_ws;
  // liveness-aliased layout, 142.6 MB total
  u16* wqkvT = (u16*)(ws + 0);          // 6.29 MB
  u16* woutT = (u16*)(ws + 6291456);    // 2.10 MB
  u16* w1T   = (u16*)(ws + 8388608);    // 8.39 MB
  u16* w2T   = (u16*)(ws + 16777216);   // 8.39 MB
  u16* qkv   = (u16*)(ws + 25165824);   // 50.3 MB  [b,l,3,h,d] (V region unused)
  u16* ffn1  = (u16*)(ws + 25165824);   // 67.1 MB  (aliases qkv+vt, both dead)
  u16* vtb   = (u16*)(ws + 75497472);   // 16.8 MB  [b,h,d,l] (written by QKV epi)
  u16* lnb   = (u16*)(ws + 92274688);   // 16.8 MB  (ln1 out / attn out / ln2 out)
  u16* attn  = lnb;
  float* h   = (float*)(ws + 125829120);// 33.6 MB

  // prep: 4 weight transposes (12288 blocks) + LN1 (8192 blocks), one launch
  prep_kernel<<<20480, 256, 0, stream>>>(w_qkv, wqkvT, w_out, woutT,
                                         w1, w1T, w2, w2T,
                                         x, ln1_g, ln1_b, lnb);
  // QKV: K=1024 -> ring-3 + fused V-transpose
  gemm_ring3<0, 0, 1, 1><<<1536, 256, 0, stream>>>(lnb, wqkvT, b_qkv, nullptr, qkv, vtb, 8192, 3072, 1024);
  attn_kernel<<<1024, 256, 0, stream>>>(qkv, vtb, attn);
  // out-proj: K=1024 -> ring-3
  gemm_ring3<0, 1, 0, 0><<<512, 256, 0, stream>>>(attn, woutT, b_out, x, h, nullptr, 8192, 1024, 1024);
  ln_kernel<<<8192, 256, 0, stream>>>(h, ln2_g, ln2_b, lnb);
  // FFN1: K=1024, gelu -> 2-buf (ring-3 and all 256^2 variants measured worse)
  gemm_kernel<1, 0, 1><<<2048, 256, 0, stream>>>(lnb, w1T, b1, nullptr, ffn1, 8192, 4096, 1024);
  // FFN2: K=4096 -> ring-3 counted vmcnt (long K-loop amortizes pipeline)
  gemm_ring3<0, 1, 0, 0><<<512, 256, 0, stream>>>(ffn1, w2T, b2, h, (float*)d_out, nullptr, 8192, 1024, 4096);
}

// Round 19
// 364.714 us; speedup vs baseline: 1.0538x; 1.0061x over previous
//
#include <hip/hip_runtime.h>
#include <hip/hip_bf16.h>

// ---------------------------------------------------------------------------
// TransformerBlock: LN1 -> QKV GEMM -> causal flash attn -> out-proj(+x) -> h
//                   LN2 -> FFN1(+gelu) -> FFN2(+h) -> out
// R22 = R21 + FFN1 2-D supertile remap: within each XCD chunk (8 bm x 32 bn),
//  blocks reordered into 8bm x 4bn supertiles. Resident window drops from
//  {3 bm x 32 bn: 9.2MB} to {~3 supertiles: 5.1MB} -> B-panels get all 8
//  bm-uses while L2-resident. Applied ONLY to gemm_kernel (= FFN1); R13
//  showed remaps are ~neutral-positive on the 2-buf kernel and the damage
//  was in ring-3 kernels, which keep the original map here.
// R21=R19 session best. 8-phase quadrant closed (5 attempts, ~170us).
// R19: attn Q-frag hoist. R18: combined sweep. R17: attn setprio.
// R16: prep merge. R15: VT_FUSE. GEMMs: ring-3 for QKV/out-proj/FFN2,
// 2-buf for FFN1. Zero-conflict XOR unit swizzle everywhere.
// ---------------------------------------------------------------------------

typedef float f32x4 __attribute__((ext_vector_type(4)));
typedef __bf16 bf16x8 __attribute__((ext_vector_type(8)));
typedef unsigned short u16;

#define MFMA16(a, b, c) __builtin_amdgcn_mfma_f32_16x16x32_bf16((a), (b), (c), 0, 0, 0)

#define GLL16(g, l)                                                            \
  __builtin_amdgcn_global_load_lds(                                            \
      (__attribute__((address_space(1))) void*)(g),                            \
      (__attribute__((address_space(3))) void*)(l), 16, 0, 0)

__device__ __forceinline__ u16 f2bf(float f) {
  union { float f; unsigned int u; } x; x.f = f;
  unsigned int r = x.u + 0x7fffu + ((x.u >> 16) & 1u);
  return (u16)(r >> 16);
}

// ---- prep: blocks [0,12288) = weight transposes, [12288,20480) = LN1 -------
__global__ __launch_bounds__(256) void prep_kernel(
    const float* __restrict__ w_qkv, u16* __restrict__ wqkvT,
    const float* __restrict__ w_out, u16* __restrict__ woutT,
    const float* __restrict__ w1,    u16* __restrict__ w1T,
    const float* __restrict__ w2,    u16* __restrict__ w2T,
    const float* __restrict__ x, const float* __restrict__ g,
    const float* __restrict__ b, u16* __restrict__ y)
{
  __shared__ u16 tile[32][33];
  __shared__ float red[8];
  int bid = blockIdx.x;
  int t = threadIdx.x;
  if (bid < 12288) {
    const float* W; u16* Wt; int K, N, nb, base;
    if (bid < 3072)      { W = w_qkv; Wt = wqkvT; K = 1024; N = 3072; nb = 96;  base = 0; }
    else if (bid < 4096) { W = w_out; Wt = woutT; K = 1024; N = 1024; nb = 32;  base = 3072; }
    else if (bid < 8192) { W = w1;    Wt = w1T;   K = 1024; N = 4096; nb = 128; base = 4096; }
    else                 { W = w2;    Wt = w2T;   K = 4096; N = 1024; nb = 32;  base = 8192; }
    int idx = bid - base;
    int n0 = (idx % nb) * 32, k0 = (idx / nb) * 32;
    int tr = t >> 5, tc = t & 31;
#pragma unroll
    for (int i = 0; i < 4; ++i) {
      int k = k0 + tr + i * 8;
      tile[tc][tr + i * 8] = f2bf(W[(size_t)k * N + n0 + tc]);
    }
    __syncthreads();
#pragma unroll
    for (int i = 0; i < 4; ++i) {
      int n = n0 + tr + i * 8;
      Wt[(size_t)n * K + k0 + tc] = tile[tr + i * 8][tc];
    }
  } else {
    int row = bid - 12288;
    const float4* xr = (const float4*)(x + (size_t)row * 1024);
    float4 v = xr[t];
    float s  = v.x + v.y + v.z + v.w;
    float ss = v.x*v.x + v.y*v.y + v.z*v.z + v.w*v.w;
#pragma unroll
    for (int off = 1; off < 64; off <<= 1) {
      s  += __shfl_xor(s, off);
      ss += __shfl_xor(ss, off);
    }
    int w = t >> 6;
    if ((t & 63) == 0) { red[w*2] = s; red[w*2+1] = ss; }
    __syncthreads();
    s  = red[0] + red[2] + red[4] + red[6];
    ss = red[1] + red[3] + red[5] + red[7];
    float mu  = s * (1.0f / 1024.0f);
    float var = ss * (1.0f / 1024.0f) - mu * mu;
    float rs  = rsqrtf(var + 1e-5f);
    float4 gg = ((const float4*)g)[t];
    float4 bb = ((const float4*)b)[t];
    ushort4 o;
    o.x = f2bf((v.x - mu) * rs * gg.x + bb.x);
    o.y = f2bf((v.y - mu) * rs * gg.y + bb.y);
    o.z = f2bf((v.z - mu) * rs * gg.z + bb.z);
    o.w = f2bf((v.w - mu) * rs * gg.w + bb.w);
    ((ushort4*)y)[(size_t)row * 256 + t] = o;
  }
}

// ---------------- LayerNorm: fp32 in -> bf16 out, one row per block ---------
__global__ __launch_bounds__(256) void ln_kernel(
    const float* __restrict__ x, const float* __restrict__ g,
    const float* __restrict__ b, u16* __restrict__ y)
{
  int row = blockIdx.x;
  int t = threadIdx.x;
  const float4* xr = (const float4*)(x + (size_t)row * 1024);
  float4 v = xr[t];
  float s  = v.x + v.y + v.z + v.w;
  float ss = v.x*v.x + v.y*v.y + v.z*v.z + v.w*v.w;
#pragma unroll
  for (int off = 1; off < 64; off <<= 1) {
    s  += __shfl_xor(s, off);
    ss += __shfl_xor(ss, off);
  }
  __shared__ float red[8];
  int w = t >> 6;
  if ((t & 63) == 0) { red[w*2] = s; red[w*2+1] = ss; }
  __syncthreads();
  s  = red[0] + red[2] + red[4] + red[6];
  ss = red[1] + red[3] + red[5] + red[7];
  float mu  = s * (1.0f / 1024.0f);
  float var = ss * (1.0f / 1024.0f) - mu * mu;
  float rs  = rsqrtf(var + 1e-5f);
  float4 gg = ((const float4*)g)[t];
  float4 bb = ((const float4*)b)[t];
  ushort4 o;
  o.x = f2bf((v.x - mu) * rs * gg.x + bb.x);
  o.y = f2bf((v.y - mu) * rs * gg.y + bb.y);
  o.z = f2bf((v.z - mu) * rs * gg.z + bb.z);
  o.w = f2bf((v.w - mu) * rs * gg.w + bb.w);
  ((ushort4*)y)[(size_t)row * 256 + t] = o;
}

// ------------------------- GEMM 128x128 2-buf (R7, verified) ----------------
// FFN1 only. R22: within-XCD 2-D supertile remap (8 bm x 4 bn) when the
// grid matches FFN1's shape (nbn==32, chunk%32==0) — shrinks the per-XCD
// L2 working set from ~9.2MB (3 bm rows x all 32 bn) to ~5.1MB.
template<int GELU, int HAS_RES, int OUT_BF16>
__global__ __launch_bounds__(256, 2) void gemm_kernel(
    const u16* __restrict__ A, const u16* __restrict__ Bt,
    const float* __restrict__ bias, const float* __restrict__ res,
    void* __restrict__ Cout, int M, int N, int K)
{
  __shared__ u16 lA[2][128 * 32];
  __shared__ u16 lB[2][128 * 32];
  const int nbn = N >> 7;
  int nwg = gridDim.x;
  int wg = blockIdx.x;
  int bm, bn;
  if (nbn == 32 && (nwg & 7) == 0 && ((nwg >> 3) & 31) == 0) {
    // XCD chunk = chunkbm bm-rows x 32 bn; reorder into 8bm x 4bn supertiles
    int xcd = wg & 7, idx = wg >> 3;
    int chunkbm = (nwg >> 3) >> 5;      // bm rows per chunk (8 for FFN1)
    int st = idx >> 5, s = idx & 31;    // supertile (bn-group), intra index
    bm = xcd * chunkbm + (s >> 2);
    bn = st * 4 + (s & 3);
  } else {
    if ((nwg & 7) == 0) wg = (wg & 7) * (nwg >> 3) + (wg >> 3);
    bm = wg / nbn; bn = wg % nbn;
  }
  int tid = threadIdx.x;
  int w = tid >> 6, l = tid & 63;
  int lh = l & 15, lg = l >> 4;
  int wr = w >> 1, wc = w & 1;
  const size_t Kb = (size_t)K * 2;
  const char* Ab = (const char*)A + (size_t)(bm * 128) * Kb;
  const char* Bb = (const char*)Bt + (size_t)(bn * 128) * Kb;

  int c0 = w * 64 + l;
  int r0 = c0 >> 2, sw0 = ((c0 ^ (c0 >> 3)) & 3) << 4;
  int c1 = (4 + w) * 64 + l;
  int r1 = c1 >> 2, sw1 = ((c1 ^ (c1 >> 3)) & 3) << 4;

#define GSTAGE(sel, kt)                                                        \
  do {                                                                         \
    GLL16(Ab + (size_t)r0 * Kb + (size_t)(kt) * 64 + sw0,                      \
          (char*)lA[sel] + w * 1024);                                          \
    GLL16(Bb + (size_t)r0 * Kb + (size_t)(kt) * 64 + sw0,                      \
          (char*)lB[sel] + w * 1024);                                          \
    GLL16(Ab + (size_t)r1 * Kb + (size_t)(kt) * 64 + sw1,                      \
          (char*)lA[sel] + (4 + w) * 1024);                                    \
    GLL16(Bb + (size_t)r1 * Kb + (size_t)(kt) * 64 + sw1,                      \
          (char*)lB[sel] + (4 + w) * 1024);                                    \
  } while (0)

  const int swo = ((lg ^ (lh >> 1)) & 3) << 4;
  const int offA = (wr * 64 + lh) * 64 + swo;
  const int offB = (wc * 64 + lh) * 64 + swo;

  f32x4 acc[4][4] = {};
  const int nkt = K >> 5;
  GSTAGE(0, 0);
  __syncthreads();
  int cur = 0;
#pragma unroll 1
  for (int kt = 0; kt < nkt; ++kt) {
    if (kt + 1 < nkt) GSTAGE(cur ^ 1, kt + 1);
    const char* bufA = (const char*)lA[cur];
    const char* bufB = (const char*)lB[cur];
    bf16x8 af[4], bfr[4];
#pragma unroll
    for (int m = 0; m < 4; ++m)
      af[m] = *(const bf16x8*)(bufA + offA + m * 1024);
#pragma unroll
    for (int n = 0; n < 4; ++n)
      bfr[n] = *(const bf16x8*)(bufB + offB + n * 1024);
#pragma unroll
    for (int m = 0; m < 4; ++m)
#pragma unroll
      for (int n = 0; n < 4; ++n)
        acc[m][n] = MFMA16(af[m], bfr[n], acc[m][n]);
    __syncthreads();
    cur ^= 1;
  }
#undef GSTAGE

#pragma unroll
  for (int m = 0; m < 4; ++m) {
    int row0 = bm * 128 + wr * 64 + m * 16 + lg * 4;
#pragma unroll
    for (int n = 0; n < 4; ++n) {
      int col = bn * 128 + wc * 64 + n * 16 + lh;
      float bv = bias[col];
#pragma unroll
      for (int r = 0; r < 4; ++r) {
        int row = row0 + r;
        float v = acc[m][n][r] + bv;
        if (GELU) v = 0.5f * v * (1.0f + erff(v * 0.70710678118f));
        if (HAS_RES) v += res[(size_t)row * N + col];
        if (OUT_BF16) ((u16*)Cout)[(size_t)row * N + col] = f2bf(v);
        else ((float*)Cout)[(size_t)row * N + col] = v;
      }
    }
  }
  (void)M;
}

// --------------------- GEMM 128x128 ring-3 (R5, verified) -------------------
template<int GELU, int HAS_RES, int OUT_BF16, int VT_FUSE>
__global__ __launch_bounds__(256, 2) void gemm_ring3(
    const u16* __restrict__ A, const u16* __restrict__ Bt,
    const float* __restrict__ bias, const float* __restrict__ res,
    void* __restrict__ Cout, u16* __restrict__ vt, int M, int N, int K)
{
  __shared__ u16 lA[3][128 * 32];
  __shared__ u16 lB[3][128 * 32];
  const int nbn = N >> 7;
  int nwg = gridDim.x;
  int wg = blockIdx.x;
  if ((nwg & 7) == 0) wg = (wg & 7) * (nwg >> 3) + (wg >> 3);
  int bm = wg / nbn, bn = wg % nbn;
  int tid = threadIdx.x;
  int w = tid >> 6, l = tid & 63;
  int lh = l & 15, lg = l >> 4;
  int wr = w >> 1, wc = w & 1;
  const size_t Kb = (size_t)K * 2;
  const char* Ab = (const char*)A + (size_t)(bm * 128) * Kb;
  const char* Bb = (const char*)Bt + (size_t)(bn * 128) * Kb;

  int c0 = w * 64 + l;
  int r0 = c0 >> 2, sw0 = ((c0 ^ (c0 >> 3)) & 3) << 4;
  int c1 = (4 + w) * 64 + l;
  int r1 = c1 >> 2, sw1 = ((c1 ^ (c1 >> 3)) & 3) << 4;

#define GSTAGE(sel, kt)                                                        \
  do {                                                                         \
    GLL16(Ab + (size_t)r0 * Kb + (size_t)(kt) * 64 + sw0,                      \
          (char*)lA[sel] + w * 1024);                                          \
    GLL16(Bb + (size_t)r0 * Kb + (size_t)(kt) * 64 + sw0,                      \
          (char*)lB[sel] + w * 1024);                                          \
    GLL16(Ab + (size_t)r1 * Kb + (size_t)(kt) * 64 + sw1,                      \
          (char*)lA[sel] + (4 + w) * 1024);                                    \
    GLL16(Bb + (size_t)r1 * Kb + (size_t)(kt) * 64 + sw1,                      \
          (char*)lB[sel] + (4 + w) * 1024);                                    \
  } while (0)

  const int swo = ((lg ^ (lh >> 1)) & 3) << 4;
  const int offA = (wr * 64 + lh) * 64 + swo;
  const int offB = (wc * 64 + lh) * 64 + swo;

  f32x4 acc[4][4] = {};
  const int nkt = K >> 5;
  GSTAGE(0, 0);
  GSTAGE(1, 1);
  asm volatile("s_waitcnt vmcnt(4)" ::: "memory");   // tile 0 resident
  __builtin_amdgcn_s_barrier();
  __builtin_amdgcn_sched_barrier(0);

  int cur = 0, s2 = 2;
#pragma unroll 1
  for (int t = 0; t < nkt; ++t) {
    const char* bufA = (const char*)lA[cur];
    const char* bufB = (const char*)lB[cur];
    bf16x8 af[4], bfr[4];
#pragma unroll
    for (int m = 0; m < 4; ++m)
      af[m] = *(const bf16x8*)(bufA + offA + m * 1024);
#pragma unroll
    for (int n = 0; n < 4; ++n)
      bfr[n] = *(const bf16x8*)(bufB + offB + n * 1024);
    if (t + 2 < nkt) GSTAGE(s2, t + 2);   // async, lands 2 steps ahead
    __builtin_amdgcn_s_setprio(1);
#pragma unroll
    for (int m = 0; m < 4; ++m)
#pragma unroll
      for (int n = 0; n < 4; ++n)
        acc[m][n] = MFMA16(af[m], bfr[n], acc[m][n]);
    __builtin_amdgcn_s_setprio(0);
    if (t < nkt - 1) {
      __builtin_amdgcn_sched_barrier(0);
      if (t < nkt - 2) asm volatile("s_waitcnt vmcnt(4)" ::: "memory");
      else             asm volatile("s_waitcnt vmcnt(0)" ::: "memory");
      __builtin_amdgcn_s_barrier();      // tile t+1 resident for all waves
      __builtin_amdgcn_sched_barrier(0);
    }
    cur = (cur == 2) ? 0 : cur + 1;
    s2  = (s2 == 2) ? 0 : s2 + 1;
  }
#undef GSTAGE

#pragma unroll
  for (int m = 0; m < 4; ++m) {
    int row0 = bm * 128 + wr * 64 + m * 16 + lg * 4;
#pragma unroll
    for (int n = 0; n < 4; ++n) {
      int col = bn * 128 + wc * 64 + n * 16 + lh;
      float bv = bias[col];
      if (VT_FUSE && col >= 2048) {
        // V block: write transposed to vtb[b,h,d,l]. Wave-uniform branch.
        int hh = (col - 2048) >> 6, dd = (col - 2048) & 63;
        int bb = row0 >> 11, ll = row0 & 2047;   // rows 4-aligned, same b
        ushort4 pk;
        pk.x = f2bf(acc[m][n][0] + bv);
        pk.y = f2bf(acc[m][n][1] + bv);
        pk.z = f2bf(acc[m][n][2] + bv);
        pk.w = f2bf(acc[m][n][3] + bv);
        *(ushort4*)(vt + ((size_t)((bb * 16 + hh) * 64 + dd)) * 2048 + ll) = pk;
      } else {
#pragma unroll
        for (int r = 0; r < 4; ++r) {
          int row = row0 + r;
          float v = acc[m][n][r] + bv;
          if (GELU) v = 0.5f * v * (1.0f + erff(v * 0.70710678118f));
          if (HAS_RES) v += res[(size_t)row * N + col];
          if (OUT_BF16) ((u16*)Cout)[(size_t)row * N + col] = f2bf(v);
          else ((float*)Cout)[(size_t)row * N + col] = v;
        }
      }
    }
  }
  (void)M;
}

// --------------------------- causal flash attention -------------------------
// R18: combined sweep — q-tiles A=pi and B=31-pi share one K/V staging pass
// (kt=0..31-pi; A active while kt<=pi). R19: A's Q frags hoisted to registers
// (loop-invariant). R17: setprio around MFMA clusters.
__global__ __launch_bounds__(256, 4) void attn_kernel(
    const u16* __restrict__ qkv, const u16* __restrict__ vt,
    u16* __restrict__ out)
{
  __shared__ u16 Ks[2][4096];
  __shared__ u16 Vs[2][4096];
  __shared__ u16 Ps[4][1024];

  const float C = 0.18033688011f;  // 0.125 * log2(e)

  int bid = blockIdx.x;
  int pi = bid >> 6, bh = bid & 63;
  int b = bh >> 4, h = bh & 15;
  int tid = threadIdx.x;
  int w = tid >> 6, l = tid & 63;
  int lh = l & 15, lg = l >> 4;
  int lh7 = lh & 7;

  const char* kg = (const char*)qkv + (size_t)(b * 2048) * 6144 + 2048 + h * 128;
  const char* vg = (const char*)vt + (size_t)((b * 16 + h) * 64) * 4096;
  char* pbw = (char*)Ps[w] + lh * 128;

  const int qbA = pi, qbB = 31 - pi;
  const int q0A = qbA * 64 + w * 16, q0B = qbB * 64 + w * 16;
  const u16* qApt = qkv + ((size_t)(b * 2048) + q0A) * 3072 + h * 64;
  const u16* qBpt = qkv + ((size_t)(b * 2048) + q0B) * 3072 + h * 64;
  bf16x8 aqA0 = *(const bf16x8*)(qApt + (size_t)lh * 3072 + lg * 8);
  bf16x8 aqA1 = *(const bf16x8*)(qApt + (size_t)lh * 3072 + 32 + lg * 8);
  bf16x8 aqB0 = *(const bf16x8*)(qBpt + (size_t)lh * 3072 + lg * 8);
  bf16x8 aqB1 = *(const bf16x8*)(qBpt + (size_t)lh * 3072 + 32 + lg * 8);

  f32x4 oA[4] = {}, oB[4] = {};
  float mA = -1e30f, lsA = 0.f, mB = -1e30f, lsB = 0.f;
  const int nt = qbB + 1;   // 32 - pi

#pragma unroll
  for (int i = 0; i < 2; ++i) {
    int u = tid + i * 256;
    int row = u >> 3, uc = u & 7, sw = uc ^ (row & 7);
    GLL16(kg + (size_t)row * 6144 + sw * 16,
          (char*)Ks[0] + (size_t)(i * 256 + w * 64) * 16);
    GLL16(vg + (size_t)row * 4096 + sw * 16,
          (char*)Vs[0] + (size_t)(i * 256 + w * 64) * 16);
  }

#pragma unroll 1
  for (int kt = 0; kt < nt; ++kt) {
    int cur = kt & 1;
    __syncthreads();
    if (kt + 1 < nt) {
      int nxt = cur ^ 1;
      size_t kofs = (size_t)(kt + 1) * 64;
#pragma unroll
      for (int i = 0; i < 2; ++i) {
        int u = tid + i * 256;
        int row = u >> 3, uc = u & 7, sw = uc ^ (row & 7);
        GLL16(kg + (kofs + row) * 6144 + sw * 16,
              (char*)Ks[nxt] + (size_t)(i * 256 + w * 64) * 16);
        GLL16(vg + (size_t)row * 4096 + kofs * 2 + sw * 16,
              (char*)Vs[nxt] + (size_t)(i * 256 + w * 64) * 16);
      }
    }
    const char* kbuf = (const char*)Ks[cur];
    const char* vbuf = (const char*)Vs[cur];

    // ================= q-tile B (always active) =================
    {
      f32x4 s[4];
      __builtin_amdgcn_s_setprio(1);
#pragma unroll
      for (int kb = 0; kb < 4; ++kb) {
        int row = kb * 16 + lh;
        const char* rp = kbuf + row * 128;
        bf16x8 a0 = *(const bf16x8*)(rp + ((lg ^ lh7) << 4));
        bf16x8 a1 = *(const bf16x8*)(rp + (((4 + lg) ^ lh7) << 4));
        f32x4 z = {0.f, 0.f, 0.f, 0.f};
        z = MFMA16(a0, aqB0, z);
        z = MFMA16(a1, aqB1, z);
        s[kb] = z;
      }
      __builtin_amdgcn_s_setprio(0);
      if (kt == qbB) {
        int qin = w * 16 + lh;
#pragma unroll
        for (int kb = 0; kb < 4; ++kb)
#pragma unroll
          for (int r = 0; r < 4; ++r)
            if (kb * 16 + lg * 4 + r > qin) s[kb][r] = -1e30f;
      }
      float tm = fmaxf(fmaxf(s[0][0], s[0][1]), fmaxf(s[0][2], s[0][3]));
#pragma unroll
      for (int kb = 1; kb < 4; ++kb)
        tm = fmaxf(tm, fmaxf(fmaxf(s[kb][0], s[kb][1]), fmaxf(s[kb][2], s[kb][3])));
      tm = fmaxf(tm, __shfl_xor(tm, 16));
      tm = fmaxf(tm, __shfl_xor(tm, 32));
      if (__any(tm > mB + 64.0f)) {
        float nm = fmaxf(mB, tm);
        float f = __builtin_amdgcn_exp2f((mB - nm) * C);
        mB = nm; lsB *= f;
#pragma unroll
        for (int db = 0; db < 4; ++db)
#pragma unroll
          for (int r = 0; r < 4; ++r) oB[db][r] *= f;
      }
      float mc = mB * C;
      float ps = 0.f;
#pragma unroll
      for (int kb = 0; kb < 4; ++kb)
#pragma unroll
        for (int r = 0; r < 4; ++r) {
          float p = __builtin_amdgcn_exp2f(fmaf(s[kb][r], C, -mc));
          s[kb][r] = p;
          ps += p;
        }
      ps += __shfl_xor(ps, 16);
      ps += __shfl_xor(ps, 32);
      lsB += ps;
#pragma unroll
      for (int kb = 0; kb < 4; ++kb) {
        unsigned lo, hi;
        asm("v_cvt_pk_bf16_f32 %0, %1, %2" : "=v"(lo) : "v"(s[kb][0]), "v"(s[kb][1]));
        asm("v_cvt_pk_bf16_f32 %0, %1, %2" : "=v"(hi) : "v"(s[kb][2]), "v"(s[kb][3]));
        int unit = kb * 2 + (lg >> 1);
        uint2 val; val.x = lo; val.y = hi;
        *(uint2*)(pbw + ((unit ^ lh7) << 4) + ((lg & 1) << 3)) = val;
      }
      bf16x8 pa0 = *(const bf16x8*)(pbw + ((lg ^ lh7) << 4));
      bf16x8 pa1 = *(const bf16x8*)(pbw + (((4 + lg) ^ lh7) << 4));
      __builtin_amdgcn_s_setprio(1);
#pragma unroll
      for (int db = 0; db < 4; ++db) {
        int row = db * 16 + lh;
        const char* rp = vbuf + row * 128;
        bf16x8 v0 = *(const bf16x8*)(rp + ((lg ^ lh7) << 4));
        bf16x8 v1 = *(const bf16x8*)(rp + (((4 + lg) ^ lh7) << 4));
        oB[db] = MFMA16(v0, pa0, oB[db]);
        oB[db] = MFMA16(v1, pa1, oB[db]);
      }
      __builtin_amdgcn_s_setprio(0);
    }

    // ================= q-tile A (active while kt <= qbA) =================
    if (kt <= qbA) {   // block-uniform branch
      f32x4 s[4];
      __builtin_amdgcn_s_setprio(1);
#pragma unroll
      for (int kb = 0; kb < 4; ++kb) {
        int row = kb * 16 + lh;
        const char* rp = kbuf + row * 128;
        bf16x8 a0 = *(const bf16x8*)(rp + ((lg ^ lh7) << 4));
        bf16x8 a1 = *(const bf16x8*)(rp + (((4 + lg) ^ lh7) << 4));
        f32x4 z = {0.f, 0.f, 0.f, 0.f};
        z = MFMA16(a0, aqA0, z);
        z = MFMA16(a1, aqA1, z);
        s[kb] = z;
      }
      __builtin_amdgcn_s_setprio(0);
      if (kt == qbA) {
        int qin = w * 16 + lh;
#pragma unroll
        for (int kb = 0; kb < 4; ++kb)
#pragma unroll
          for (int r = 0; r < 4; ++r)
            if (kb * 16 + lg * 4 + r > qin) s[kb][r] = -1e30f;
      }
      float tm = fmaxf(fmaxf(s[0][0], s[0][1]), fmaxf(s[0][2], s[0][3]));
#pragma unroll
      for (int kb = 1; kb < 4; ++kb)
        tm = fmaxf(tm, fmaxf(fmaxf(s[kb][0], s[kb][1]), fmaxf(s[kb][2], s[kb][3])));
      tm = fmaxf(tm, __shfl_xor(tm, 16));
      tm = fmaxf(tm, __shfl_xor(tm, 32));
      if (__any(tm > mA + 64.0f)) {
        float nm = fmaxf(mA, tm);
        float f = __builtin_amdgcn_exp2f((mA - nm) * C);
        mA = nm; lsA *= f;
#pragma unroll
        for (int db = 0; db < 4; ++db)
#pragma unroll
          for (int r = 0; r < 4; ++r) oA[db][r] *= f;
      }
      float mc = mA * C;
      float ps = 0.f;
#pragma unroll
      for (int kb = 0; kb < 4; ++kb)
#pragma unroll
        for (int r = 0; r < 4; ++r) {
          float p = __builtin_amdgcn_exp2f(fmaf(s[kb][r], C, -mc));
          s[kb][r] = p;
          ps += p;
        }
      ps += __shfl_xor(ps, 16);
      ps += __shfl_xor(ps, 32);
      lsA += ps;
#pragma unroll
      for (int kb = 0; kb < 4; ++kb) {
        unsigned lo, hi;
        asm("v_cvt_pk_bf16_f32 %0, %1, %2" : "=v"(lo) : "v"(s[kb][0]), "v"(s[kb][1]));
        asm("v_cvt_pk_bf16_f32 %0, %1, %2" : "=v"(hi) : "v"(s[kb][2]), "v"(s[kb][3]));
        int unit = kb * 2 + (lg >> 1);
        uint2 val; val.x = lo; val.y = hi;
        *(uint2*)(pbw + ((unit ^ lh7) << 4) + ((lg & 1) << 3)) = val;
      }
      bf16x8 pa0 = *(const bf16x8*)(pbw + ((lg ^ lh7) << 4));
      bf16x8 pa1 = *(const bf16x8*)(pbw + (((4 + lg) ^ lh7) << 4));
      __builtin_amdgcn_s_setprio(1);
#pragma unroll
      for (int db = 0; db < 4; ++db) {
        int row = db * 16 + lh;
        const char* rp = vbuf + row * 128;
        bf16x8 v0 = *(const bf16x8*)(rp + ((lg ^ lh7) << 4));
        bf16x8 v1 = *(const bf16x8*)(rp + (((4 + lg) ^ lh7) << 4));
        oA[db] = MFMA16(v0, pa0, oA[db]);
        oA[db] = MFMA16(v1, pa1, oA[db]);
      }
      __builtin_amdgcn_s_setprio(0);
    }
  }

  {
    float rinv = 1.0f / lsB;
    u16* ob = out + ((size_t)(b * 2048) + q0B + lh) * 1024 + h * 64;
#pragma unroll
    for (int db = 0; db < 4; ++db) {
      ushort4 pk;
      pk.x = f2bf(oB[db][0] * rinv);
      pk.y = f2bf(oB[db][1] * rinv);
      pk.z = f2bf(oB[db][2] * rinv);
      pk.w = f2bf(oB[db][3] * rinv);
      *(ushort4*)(ob + db * 16 + lg * 4) = pk;
    }
  }
  {
    float rinv = 1.0f / lsA;
    u16* ob = out + ((size_t)(b * 2048) + q0A + lh) * 1024 + h * 64;
#pragma unroll
    for (int db = 0; db < 4; ++db) {
      ushort4 pk;
      pk.x = f2bf(oA[db][0] * rinv);
      pk.y = f2bf(oA[db][1] * rinv);
      pk.z = f2bf(oA[db][2] * rinv);
      pk.w = f2bf(oA[db][3] * rinv);
      *(ushort4*)(ob + db * 16 + lg * 4) = pk;
    }
  }
}

// ---------------------------------------------------------------------------
extern "C" void kernel_launch(void* const* d_in, const int* in_sizes, int n_in,
                              void* d_out, int out_size, void* d_ws, size_t ws_size,
                              hipStream_t stream) {
  const float* x     = (const float*)d_in[0];
  const float* ln1_g = (const float*)d_in[1];
  const float* ln1_b = (const float*)d_in[2];
  const float* w_qkv = (const float*)d_in[3];
  const float* b_qkv = (const float*)d_in[4];
  const float* w_out = (const float*)d_in[5];
  const float* b_out = (const float*)d_in[6];
  const float* ln2_g = (const float*)d_in[7];
  const float* ln2_b = (const float*)d_in[8];
  const float* w1    = (const float*)d_in[9];
  const float* b1    = (const float*)d_in[10];
  const float* w2    = (const float*)d_in[11];
  const float* b2    = (const float*)d_in[12];

  char* ws = (char*)d_ws;
  // liveness-aliased layout, 142.6 MB total
  u16* wqkvT = (u16*)(ws + 0);          // 6.29 MB
  u16* woutT = (u16*)(ws + 6291456);    // 2.10 MB
  u16* w1T   = (u16*)(ws + 8388608);    // 8.39 MB
  u16* w2T   = (u16*)(ws + 16777216);   // 8.39 MB
  u16* qkv   = (u16*)(ws + 25165824);   // 50.3 MB  [b,l,3,h,d] (V region unused)
  u16* ffn1  = (u16*)(ws + 25165824);   // 67.1 MB  (aliases qkv+vt, both dead)
  u16* vtb   = (u16*)(ws + 75497472);   // 16.8 MB  [b,h,d,l] (written by QKV epi)
  u16* lnb   = (u16*)(ws + 92274688);   // 16.8 MB  (ln1 out / attn out / ln2 out)
  u16* attn  = lnb;
  float* h   = (float*)(ws + 125829120);// 33.6 MB

  // prep: 4 weight transposes (12288 blocks) + LN1 (8192 blocks), one launch
  prep_kernel<<<20480, 256, 0, stream>>>(w_qkv, wqkvT, w_out, woutT,
                                         w1, w1T, w2, w2T,
                                         x, ln1_g, ln1_b, lnb);
  // QKV: K=1024 -> ring-3 + fused V-transpose
  gemm_ring3<0, 0, 1, 1><<<1536, 256, 0, stream>>>(lnb, wqkvT, b_qkv, nullptr, qkv, vtb, 8192, 3072, 1024);
  attn_kernel<<<1024, 256, 0, stream>>>(qkv, vtb, attn);
  // out-proj: K=1024 -> ring-3
  gemm_ring3<0, 1, 0, 0><<<512, 256, 0, stream>>>(attn, woutT, b_out, x, h, nullptr, 8192, 1024, 1024);
  ln_kernel<<<8192, 256, 0, stream>>>(h, ln2_g, ln2_b, lnb);
  // FFN1: K=1024, gelu -> 2-buf + 2-D supertile remap (L2 working-set fit)
  gemm_kernel<1, 0, 1><<<2048, 256, 0, stream>>>(lnb, w1T, b1, nullptr, ffn1, 8192, 4096, 1024);
  // FFN2: K=4096 -> ring-3 counted vmcnt (long K-loop amortizes pipeline)
  gemm_ring3<0, 1, 0, 0><<<512, 256, 0, stream>>>(ffn1, w2T, b2, h, (float*)d_out, nullptr, 8192, 1024, 4096);
}

// Round 20
// 362.168 us; speedup vs baseline: 1.0612x; 1.0070x over previous
//
#include <hip/hip_runtime.h>
#include <hip/hip_bf16.h>

// ---------------------------------------------------------------------------
// TransformerBlock: LN1 -> QKV GEMM -> causal flash attn -> out-proj(+x) -> h
//                   LN2 -> FFN1(+gelu) -> FFN2(+h) -> out
// R23 = R22 + QKV 2-D supertile remap (same verified mechanism): within each
//  XCD chunk (8 bm x 24 bn), blocks reordered into 8bm x 4bn supertiles ->
//  per-XCD L2 window ~7.1MB -> ~5MB. Gated nbn==24 (QKV only); out-proj/FFN2
//  (nbn=8) already L2-fit, FFN2's K=4096 panels would not.
// R22: FFN1 supertile remap — verified: FETCH 74 -> 49.4MB, dur 135 -> 131.
// R21=R19 base. 8-phase quadrant closed (5 attempts ~170us).
// R19: attn Q-frag hoist. R18: combined sweep. R17: attn setprio.
// R16: prep merge. R15: VT_FUSE. GEMMs: ring-3 for QKV/out-proj/FFN2,
// 2-buf for FFN1. Zero-conflict XOR unit swizzle everywhere.
// ---------------------------------------------------------------------------

typedef float f32x4 __attribute__((ext_vector_type(4)));
typedef __bf16 bf16x8 __attribute__((ext_vector_type(8)));
typedef unsigned short u16;

#define MFMA16(a, b, c) __builtin_amdgcn_mfma_f32_16x16x32_bf16((a), (b), (c), 0, 0, 0)

#define GLL16(g, l)                                                            \
  __builtin_amdgcn_global_load_lds(                                            \
      (__attribute__((address_space(1))) void*)(g),                            \
      (__attribute__((address_space(3))) void*)(l), 16, 0, 0)

__device__ __forceinline__ u16 f2bf(float f) {
  union { float f; unsigned int u; } x; x.f = f;
  unsigned int r = x.u + 0x7fffu + ((x.u >> 16) & 1u);
  return (u16)(r >> 16);
}

// ---- prep: blocks [0,12288) = weight transposes, [12288,20480) = LN1 -------
__global__ __launch_bounds__(256) void prep_kernel(
    const float* __restrict__ w_qkv, u16* __restrict__ wqkvT,
    const float* __restrict__ w_out, u16* __restrict__ woutT,
    const float* __restrict__ w1,    u16* __restrict__ w1T,
    const float* __restrict__ w2,    u16* __restrict__ w2T,
    const float* __restrict__ x, const float* __restrict__ g,
    const float* __restrict__ b, u16* __restrict__ y)
{
  __shared__ u16 tile[32][33];
  __shared__ float red[8];
  int bid = blockIdx.x;
  int t = threadIdx.x;
  if (bid < 12288) {
    const float* W; u16* Wt; int K, N, nb, base;
    if (bid < 3072)      { W = w_qkv; Wt = wqkvT; K = 1024; N = 3072; nb = 96;  base = 0; }
    else if (bid < 4096) { W = w_out; Wt = woutT; K = 1024; N = 1024; nb = 32;  base = 3072; }
    else if (bid < 8192) { W = w1;    Wt = w1T;   K = 1024; N = 4096; nb = 128; base = 4096; }
    else                 { W = w2;    Wt = w2T;   K = 4096; N = 1024; nb = 32;  base = 8192; }
    int idx = bid - base;
    int n0 = (idx % nb) * 32, k0 = (idx / nb) * 32;
    int tr = t >> 5, tc = t & 31;
#pragma unroll
    for (int i = 0; i < 4; ++i) {
      int k = k0 + tr + i * 8;
      tile[tc][tr + i * 8] = f2bf(W[(size_t)k * N + n0 + tc]);
    }
    __syncthreads();
#pragma unroll
    for (int i = 0; i < 4; ++i) {
      int n = n0 + tr + i * 8;
      Wt[(size_t)n * K + k0 + tc] = tile[tr + i * 8][tc];
    }
  } else {
    int row = bid - 12288;
    const float4* xr = (const float4*)(x + (size_t)row * 1024);
    float4 v = xr[t];
    float s  = v.x + v.y + v.z + v.w;
    float ss = v.x*v.x + v.y*v.y + v.z*v.z + v.w*v.w;
#pragma unroll
    for (int off = 1; off < 64; off <<= 1) {
      s  += __shfl_xor(s, off);
      ss += __shfl_xor(ss, off);
    }
    int w = t >> 6;
    if ((t & 63) == 0) { red[w*2] = s; red[w*2+1] = ss; }
    __syncthreads();
    s  = red[0] + red[2] + red[4] + red[6];
    ss = red[1] + red[3] + red[5] + red[7];
    float mu  = s * (1.0f / 1024.0f);
    float var = ss * (1.0f / 1024.0f) - mu * mu;
    float rs  = rsqrtf(var + 1e-5f);
    float4 gg = ((const float4*)g)[t];
    float4 bb = ((const float4*)b)[t];
    ushort4 o;
    o.x = f2bf((v.x - mu) * rs * gg.x + bb.x);
    o.y = f2bf((v.y - mu) * rs * gg.y + bb.y);
    o.z = f2bf((v.z - mu) * rs * gg.z + bb.z);
    o.w = f2bf((v.w - mu) * rs * gg.w + bb.w);
    ((ushort4*)y)[(size_t)row * 256 + t] = o;
  }
}

// ---------------- LayerNorm: fp32 in -> bf16 out, one row per block ---------
__global__ __launch_bounds__(256) void ln_kernel(
    const float* __restrict__ x, const float* __restrict__ g,
    const float* __restrict__ b, u16* __restrict__ y)
{
  int row = blockIdx.x;
  int t = threadIdx.x;
  const float4* xr = (const float4*)(x + (size_t)row * 1024);
  float4 v = xr[t];
  float s  = v.x + v.y + v.z + v.w;
  float ss = v.x*v.x + v.y*v.y + v.z*v.z + v.w*v.w;
#pragma unroll
  for (int off = 1; off < 64; off <<= 1) {
    s  += __shfl_xor(s, off);
    ss += __shfl_xor(ss, off);
  }
  __shared__ float red[8];
  int w = t >> 6;
  if ((t & 63) == 0) { red[w*2] = s; red[w*2+1] = ss; }
  __syncthreads();
  s  = red[0] + red[2] + red[4] + red[6];
  ss = red[1] + red[3] + red[5] + red[7];
  float mu  = s * (1.0f / 1024.0f);
  float var = ss * (1.0f / 1024.0f) - mu * mu;
  float rs  = rsqrtf(var + 1e-5f);
  float4 gg = ((const float4*)g)[t];
  float4 bb = ((const float4*)b)[t];
  ushort4 o;
  o.x = f2bf((v.x - mu) * rs * gg.x + bb.x);
  o.y = f2bf((v.y - mu) * rs * gg.y + bb.y);
  o.z = f2bf((v.z - mu) * rs * gg.z + bb.z);
  o.w = f2bf((v.w - mu) * rs * gg.w + bb.w);
  ((ushort4*)y)[(size_t)row * 256 + t] = o;
}

// ------------------------- GEMM 128x128 2-buf (R7, verified) ----------------
// FFN1 only. R22: within-XCD 2-D supertile remap (8 bm x 4 bn) — verified:
// FETCH 74 -> 49.4MB, dur 135 -> 131us.
template<int GELU, int HAS_RES, int OUT_BF16>
__global__ __launch_bounds__(256, 2) void gemm_kernel(
    const u16* __restrict__ A, const u16* __restrict__ Bt,
    const float* __restrict__ bias, const float* __restrict__ res,
    void* __restrict__ Cout, int M, int N, int K)
{
  __shared__ u16 lA[2][128 * 32];
  __shared__ u16 lB[2][128 * 32];
  const int nbn = N >> 7;
  int nwg = gridDim.x;
  int wg = blockIdx.x;
  int bm, bn;
  if (nbn == 32 && (nwg & 7) == 0 && ((nwg >> 3) & 31) == 0) {
    int xcd = wg & 7, idx = wg >> 3;
    int chunkbm = (nwg >> 3) >> 5;      // bm rows per chunk (8 for FFN1)
    int st = idx >> 5, s = idx & 31;    // supertile (bn-group), intra index
    bm = xcd * chunkbm + (s >> 2);
    bn = st * 4 + (s & 3);
  } else {
    if ((nwg & 7) == 0) wg = (wg & 7) * (nwg >> 3) + (wg >> 3);
    bm = wg / nbn; bn = wg % nbn;
  }
  int tid = threadIdx.x;
  int w = tid >> 6, l = tid & 63;
  int lh = l & 15, lg = l >> 4;
  int wr = w >> 1, wc = w & 1;
  const size_t Kb = (size_t)K * 2;
  const char* Ab = (const char*)A + (size_t)(bm * 128) * Kb;
  const char* Bb = (const char*)Bt + (size_t)(bn * 128) * Kb;

  int c0 = w * 64 + l;
  int r0 = c0 >> 2, sw0 = ((c0 ^ (c0 >> 3)) & 3) << 4;
  int c1 = (4 + w) * 64 + l;
  int r1 = c1 >> 2, sw1 = ((c1 ^ (c1 >> 3)) & 3) << 4;

#define GSTAGE(sel, kt)                                                        \
  do {                                                                         \
    GLL16(Ab + (size_t)r0 * Kb + (size_t)(kt) * 64 + sw0,                      \
          (char*)lA[sel] + w * 1024);                                          \
    GLL16(Bb + (size_t)r0 * Kb + (size_t)(kt) * 64 + sw0,                      \
          (char*)lB[sel] + w * 1024);                                          \
    GLL16(Ab + (size_t)r1 * Kb + (size_t)(kt) * 64 + sw1,                      \
          (char*)lA[sel] + (4 + w) * 1024);                                    \
    GLL16(Bb + (size_t)r1 * Kb + (size_t)(kt) * 64 + sw1,                      \
          (char*)lB[sel] + (4 + w) * 1024);                                    \
  } while (0)

  const int swo = ((lg ^ (lh >> 1)) & 3) << 4;
  const int offA = (wr * 64 + lh) * 64 + swo;
  const int offB = (wc * 64 + lh) * 64 + swo;

  f32x4 acc[4][4] = {};
  const int nkt = K >> 5;
  GSTAGE(0, 0);
  __syncthreads();
  int cur = 0;
#pragma unroll 1
  for (int kt = 0; kt < nkt; ++kt) {
    if (kt + 1 < nkt) GSTAGE(cur ^ 1, kt + 1);
    const char* bufA = (const char*)lA[cur];
    const char* bufB = (const char*)lB[cur];
    bf16x8 af[4], bfr[4];
#pragma unroll
    for (int m = 0; m < 4; ++m)
      af[m] = *(const bf16x8*)(bufA + offA + m * 1024);
#pragma unroll
    for (int n = 0; n < 4; ++n)
      bfr[n] = *(const bf16x8*)(bufB + offB + n * 1024);
#pragma unroll
    for (int m = 0; m < 4; ++m)
#pragma unroll
      for (int n = 0; n < 4; ++n)
        acc[m][n] = MFMA16(af[m], bfr[n], acc[m][n]);
    __syncthreads();
    cur ^= 1;
  }
#undef GSTAGE

#pragma unroll
  for (int m = 0; m < 4; ++m) {
    int row0 = bm * 128 + wr * 64 + m * 16 + lg * 4;
#pragma unroll
    for (int n = 0; n < 4; ++n) {
      int col = bn * 128 + wc * 64 + n * 16 + lh;
      float bv = bias[col];
#pragma unroll
      for (int r = 0; r < 4; ++r) {
        int row = row0 + r;
        float v = acc[m][n][r] + bv;
        if (GELU) v = 0.5f * v * (1.0f + erff(v * 0.70710678118f));
        if (HAS_RES) v += res[(size_t)row * N + col];
        if (OUT_BF16) ((u16*)Cout)[(size_t)row * N + col] = f2bf(v);
        else ((float*)Cout)[(size_t)row * N + col] = v;
      }
    }
  }
  (void)M;
}

// --------------------- GEMM 128x128 ring-3 (R5, verified) -------------------
// R23: QKV (nbn==24) gets the R22-verified 2-D supertile remap (8bm x 4bn
// within the XCD chunk); out-proj/FFN2 (nbn==8, window already L2-fit) keep
// the original map.
template<int GELU, int HAS_RES, int OUT_BF16, int VT_FUSE>
__global__ __launch_bounds__(256, 2) void gemm_ring3(
    const u16* __restrict__ A, const u16* __restrict__ Bt,
    const float* __restrict__ bias, const float* __restrict__ res,
    void* __restrict__ Cout, u16* __restrict__ vt, int M, int N, int K)
{
  __shared__ u16 lA[3][128 * 32];
  __shared__ u16 lB[3][128 * 32];
  const int nbn = N >> 7;
  int nwg = gridDim.x;
  int wg = blockIdx.x;
  int bm, bn;
  if (nbn == 24 && (nwg & 7) == 0 && ((nwg >> 3) % 96) == 0) {
    // QKV: chunk = chunkbm bm-rows x 24 bn; supertiles of 8bm x 4bn.
    int xcd = wg & 7, idx = wg >> 3;
    int chunkbm = (nwg >> 3) / 24;      // 8 for QKV (1536 wg)
    int st = idx >> 5, s = idx & 31;    // bn-group, intra index
    bm = xcd * chunkbm + (s >> 2);
    bn = st * 4 + (s & 3);
  } else {
    if ((nwg & 7) == 0) wg = (wg & 7) * (nwg >> 3) + (wg >> 3);
    bm = wg / nbn; bn = wg % nbn;
  }
  int tid = threadIdx.x;
  int w = tid >> 6, l = tid & 63;
  int lh = l & 15, lg = l >> 4;
  int wr = w >> 1, wc = w & 1;
  const size_t Kb = (size_t)K * 2;
  const char* Ab = (const char*)A + (size_t)(bm * 128) * Kb;
  const char* Bb = (const char*)Bt + (size_t)(bn * 128) * Kb;

  int c0 = w * 64 + l;
  int r0 = c0 >> 2, sw0 = ((c0 ^ (c0 >> 3)) & 3) << 4;
  int c1 = (4 + w) * 64 + l;
  int r1 = c1 >> 2, sw1 = ((c1 ^ (c1 >> 3)) & 3) << 4;

#define GSTAGE(sel, kt)                                                        \
  do {                                                                         \
    GLL16(Ab + (size_t)r0 * Kb + (size_t)(kt) * 64 + sw0,                      \
          (char*)lA[sel] + w * 1024);                                          \
    GLL16(Bb + (size_t)r0 * Kb + (size_t)(kt) * 64 + sw0,                      \
          (char*)lB[sel] + w * 1024);                                          \
    GLL16(Ab + (size_t)r1 * Kb + (size_t)(kt) * 64 + sw1,                      \
          (char*)lA[sel] + (4 + w) * 1024);                                    \
    GLL16(Bb + (size_t)r1 * Kb + (size_t)(kt) * 64 + sw1,                      \
          (char*)lB[sel] + (4 + w) * 1024);                                    \
  } while (0)

  const int swo = ((lg ^ (lh >> 1)) & 3) << 4;
  const int offA = (wr * 64 + lh) * 64 + swo;
  const int offB = (wc * 64 + lh) * 64 + swo;

  f32x4 acc[4][4] = {};
  const int nkt = K >> 5;
  GSTAGE(0, 0);
  GSTAGE(1, 1);
  asm volatile("s_waitcnt vmcnt(4)" ::: "memory");   // tile 0 resident
  __builtin_amdgcn_s_barrier();
  __builtin_amdgcn_sched_barrier(0);

  int cur = 0, s2 = 2;
#pragma unroll 1
  for (int t = 0; t < nkt; ++t) {
    const char* bufA = (const char*)lA[cur];
    const char* bufB = (const char*)lB[cur];
    bf16x8 af[4], bfr[4];
#pragma unroll
    for (int m = 0; m < 4; ++m)
      af[m] = *(const bf16x8*)(bufA + offA + m * 1024);
#pragma unroll
    for (int n = 0; n < 4; ++n)
      bfr[n] = *(const bf16x8*)(bufB + offB + n * 1024);
    if (t + 2 < nkt) GSTAGE(s2, t + 2);   // async, lands 2 steps ahead
    __builtin_amdgcn_s_setprio(1);
#pragma unroll
    for (int m = 0; m < 4; ++m)
#pragma unroll
      for (int n = 0; n < 4; ++n)
        acc[m][n] = MFMA16(af[m], bfr[n], acc[m][n]);
    __builtin_amdgcn_s_setprio(0);
    if (t < nkt - 1) {
      __builtin_amdgcn_sched_barrier(0);
      if (t < nkt - 2) asm volatile("s_waitcnt vmcnt(4)" ::: "memory");
      else             asm volatile("s_waitcnt vmcnt(0)" ::: "memory");
      __builtin_amdgcn_s_barrier();      // tile t+1 resident for all waves
      __builtin_amdgcn_sched_barrier(0);
    }
    cur = (cur == 2) ? 0 : cur + 1;
    s2  = (s2 == 2) ? 0 : s2 + 1;
  }
#undef GSTAGE

#pragma unroll
  for (int m = 0; m < 4; ++m) {
    int row0 = bm * 128 + wr * 64 + m * 16 + lg * 4;
#pragma unroll
    for (int n = 0; n < 4; ++n) {
      int col = bn * 128 + wc * 64 + n * 16 + lh;
      float bv = bias[col];
      if (VT_FUSE && col >= 2048) {
        // V block: write transposed to vtb[b,h,d,l]. Wave-uniform branch.
        int hh = (col - 2048) >> 6, dd = (col - 2048) & 63;
        int bb = row0 >> 11, ll = row0 & 2047;   // rows 4-aligned, same b
        ushort4 pk;
        pk.x = f2bf(acc[m][n][0] + bv);
        pk.y = f2bf(acc[m][n][1] + bv);
        pk.z = f2bf(acc[m][n][2] + bv);
        pk.w = f2bf(acc[m][n][3] + bv);
        *(ushort4*)(vt + ((size_t)((bb * 16 + hh) * 64 + dd)) * 2048 + ll) = pk;
      } else {
#pragma unroll
        for (int r = 0; r < 4; ++r) {
          int row = row0 + r;
          float v = acc[m][n][r] + bv;
          if (GELU) v = 0.5f * v * (1.0f + erff(v * 0.70710678118f));
          if (HAS_RES) v += res[(size_t)row * N + col];
          if (OUT_BF16) ((u16*)Cout)[(size_t)row * N + col] = f2bf(v);
          else ((float*)Cout)[(size_t)row * N + col] = v;
        }
      }
    }
  }
  (void)M;
}

// --------------------------- causal flash attention -------------------------
// R18: combined sweep — q-tiles A=pi and B=31-pi share one K/V staging pass
// (kt=0..31-pi; A active while kt<=pi). R19: A's Q frags hoisted to registers
// (loop-invariant). R17: setprio around MFMA clusters.
__global__ __launch_bounds__(256, 4) void attn_kernel(
    const u16* __restrict__ qkv, const u16* __restrict__ vt,
    u16* __restrict__ out)
{
  __shared__ u16 Ks[2][4096];
  __shared__ u16 Vs[2][4096];
  __shared__ u16 Ps[4][1024];

  const float C = 0.18033688011f;  // 0.125 * log2(e)

  int bid = blockIdx.x;
  int pi = bid >> 6, bh = bid & 63;
  int b = bh >> 4, h = bh & 15;
  int tid = threadIdx.x;
  int w = tid >> 6, l = tid & 63;
  int lh = l & 15, lg = l >> 4;
  int lh7 = lh & 7;

  const char* kg = (const char*)qkv + (size_t)(b * 2048) * 6144 + 2048 + h * 128;
  const char* vg = (const char*)vt + (size_t)((b * 16 + h) * 64) * 4096;
  char* pbw = (char*)Ps[w] + lh * 128;

  const int qbA = pi, qbB = 31 - pi;
  const int q0A = qbA * 64 + w * 16, q0B = qbB * 64 + w * 16;
  const u16* qApt = qkv + ((size_t)(b * 2048) + q0A) * 3072 + h * 64;
  const u16* qBpt = qkv + ((size_t)(b * 2048) + q0B) * 3072 + h * 64;
  bf16x8 aqA0 = *(const bf16x8*)(qApt + (size_t)lh * 3072 + lg * 8);
  bf16x8 aqA1 = *(const bf16x8*)(qApt + (size_t)lh * 3072 + 32 + lg * 8);
  bf16x8 aqB0 = *(const bf16x8*)(qBpt + (size_t)lh * 3072 + lg * 8);
  bf16x8 aqB1 = *(const bf16x8*)(qBpt + (size_t)lh * 3072 + 32 + lg * 8);

  f32x4 oA[4] = {}, oB[4] = {};
  float mA = -1e30f, lsA = 0.f, mB = -1e30f, lsB = 0.f;
  const int nt = qbB + 1;   // 32 - pi

#pragma unroll
  for (int i = 0; i < 2; ++i) {
    int u = tid + i * 256;
    int row = u >> 3, uc = u & 7, sw = uc ^ (row & 7);
    GLL16(kg + (size_t)row * 6144 + sw * 16,
          (char*)Ks[0] + (size_t)(i * 256 + w * 64) * 16);
    GLL16(vg + (size_t)row * 4096 + sw * 16,
          (char*)Vs[0] + (size_t)(i * 256 + w * 64) * 16);
  }

#pragma unroll 1
  for (int kt = 0; kt < nt; ++kt) {
    int cur = kt & 1;
    __syncthreads();
    if (kt + 1 < nt) {
      int nxt = cur ^ 1;
      size_t kofs = (size_t)(kt + 1) * 64;
#pragma unroll
      for (int i = 0; i < 2; ++i) {
        int u = tid + i * 256;
        int row = u >> 3, uc = u & 7, sw = uc ^ (row & 7);
        GLL16(kg + (kofs + row) * 6144 + sw * 16,
              (char*)Ks[nxt] + (size_t)(i * 256 + w * 64) * 16);
        GLL16(vg + (size_t)row * 4096 + kofs * 2 + sw * 16,
              (char*)Vs[nxt] + (size_t)(i * 256 + w * 64) * 16);
      }
    }
    const char* kbuf = (const char*)Ks[cur];
    const char* vbuf = (const char*)Vs[cur];

    // ================= q-tile B (always active) =================
    {
      f32x4 s[4];
      __builtin_amdgcn_s_setprio(1);
#pragma unroll
      for (int kb = 0; kb < 4; ++kb) {
        int row = kb * 16 + lh;
        const char* rp = kbuf + row * 128;
        bf16x8 a0 = *(const bf16x8*)(rp + ((lg ^ lh7) << 4));
        bf16x8 a1 = *(const bf16x8*)(rp + (((4 + lg) ^ lh7) << 4));
        f32x4 z = {0.f, 0.f, 0.f, 0.f};
        z = MFMA16(a0, aqB0, z);
        z = MFMA16(a1, aqB1, z);
        s[kb] = z;
      }
      __builtin_amdgcn_s_setprio(0);
      if (kt == qbB) {
        int qin = w * 16 + lh;
#pragma unroll
        for (int kb = 0; kb < 4; ++kb)
#pragma unroll
          for (int r = 0; r < 4; ++r)
            if (kb * 16 + lg * 4 + r > qin) s[kb][r] = -1e30f;
      }
      float tm = fmaxf(fmaxf(s[0][0], s[0][1]), fmaxf(s[0][2], s[0][3]));
#pragma unroll
      for (int kb = 1; kb < 4; ++kb)
        tm = fmaxf(tm, fmaxf(fmaxf(s[kb][0], s[kb][1]), fmaxf(s[kb][2], s[kb][3])));
      tm = fmaxf(tm, __shfl_xor(tm, 16));
      tm = fmaxf(tm, __shfl_xor(tm, 32));
      if (__any(tm > mB + 64.0f)) {
        float nm = fmaxf(mB, tm);
        float f = __builtin_amdgcn_exp2f((mB - nm) * C);
        mB = nm; lsB *= f;
#pragma unroll
        for (int db = 0; db < 4; ++db)
#pragma unroll
          for (int r = 0; r < 4; ++r) oB[db][r] *= f;
      }
      float mc = mB * C;
      float ps = 0.f;
#pragma unroll
      for (int kb = 0; kb < 4; ++kb)
#pragma unroll
        for (int r = 0; r < 4; ++r) {
          float p = __builtin_amdgcn_exp2f(fmaf(s[kb][r], C, -mc));
          s[kb][r] = p;
          ps += p;
        }
      ps += __shfl_xor(ps, 16);
      ps += __shfl_xor(ps, 32);
      lsB += ps;
#pragma unroll
      for (int kb = 0; kb < 4; ++kb) {
        unsigned lo, hi;
        asm("v_cvt_pk_bf16_f32 %0, %1, %2" : "=v"(lo) : "v"(s[kb][0]), "v"(s[kb][1]));
        asm("v_cvt_pk_bf16_f32 %0, %1, %2" : "=v"(hi) : "v"(s[kb][2]), "v"(s[kb][3]));
        int unit = kb * 2 + (lg >> 1);
        uint2 val; val.x = lo; val.y = hi;
        *(uint2*)(pbw + ((unit ^ lh7) << 4) + ((lg & 1) << 3)) = val;
      }
      bf16x8 pa0 = *(const bf16x8*)(pbw + ((lg ^ lh7) << 4));
      bf16x8 pa1 = *(const bf16x8*)(pbw + (((4 + lg) ^ lh7) << 4));
      __builtin_amdgcn_s_setprio(1);
#pragma unroll
      for (int db = 0; db < 4; ++db) {
        int row = db * 16 + lh;
        const char* rp = vbuf + row * 128;
        bf16x8 v0 = *(const bf16x8*)(rp + ((lg ^ lh7) << 4));
        bf16x8 v1 = *(const bf16x8*)(rp + (((4 + lg) ^ lh7) << 4));
        oB[db] = MFMA16(v0, pa0, oB[db]);
        oB[db] = MFMA16(v1, pa1, oB[db]);
      }
      __builtin_amdgcn_s_setprio(0);
    }

    // ================= q-tile A (active while kt <= qbA) =================
    if (kt <= qbA) {   // block-uniform branch
      f32x4 s[4];
      __builtin_amdgcn_s_setprio(1);
#pragma unroll
      for (int kb = 0; kb < 4; ++kb) {
        int row = kb * 16 + lh;
        const char* rp = kbuf + row * 128;
        bf16x8 a0 = *(const bf16x8*)(rp + ((lg ^ lh7) << 4));
        bf16x8 a1 = *(const bf16x8*)(rp + (((4 + lg) ^ lh7) << 4));
        f32x4 z = {0.f, 0.f, 0.f, 0.f};
        z = MFMA16(a0, aqA0, z);
        z = MFMA16(a1, aqA1, z);
        s[kb] = z;
      }
      __builtin_amdgcn_s_setprio(0);
      if (kt == qbA) {
        int qin = w * 16 + lh;
#pragma unroll
        for (int kb = 0; kb < 4; ++kb)
#pragma unroll
          for (int r = 0; r < 4; ++r)
            if (kb * 16 + lg * 4 + r > qin) s[kb][r] = -1e30f;
      }
      float tm = fmaxf(fmaxf(s[0][0], s[0][1]), fmaxf(s[0][2], s[0][3]));
#pragma unroll
      for (int kb = 1; kb < 4; ++kb)
        tm = fmaxf(tm, fmaxf(fmaxf(s[kb][0], s[kb][1]), fmaxf(s[kb][2], s[kb][3])));
      tm = fmaxf(tm, __shfl_xor(tm, 16));
      tm = fmaxf(tm, __shfl_xor(tm, 32));
      if (__any(tm > mA + 64.0f)) {
        float nm = fmaxf(mA, tm);
        float f = __builtin_amdgcn_exp2f((mA - nm) * C);
        mA = nm; lsA *= f;
#pragma unroll
        for (int db = 0; db < 4; ++db)
#pragma unroll
          for (int r = 0; r < 4; ++r) oA[db][r] *= f;
      }
      float mc = mA * C;
      float ps = 0.f;
#pragma unroll
      for (int kb = 0; kb < 4; ++kb)
#pragma unroll
        for (int r = 0; r < 4; ++r) {
          float p = __builtin_amdgcn_exp2f(fmaf(s[kb][r], C, -mc));
          s[kb][r] = p;
          ps += p;
        }
      ps += __shfl_xor(ps, 16);
      ps += __shfl_xor(ps, 32);
      lsA += ps;
#pragma unroll
      for (int kb = 0; kb < 4; ++kb) {
        unsigned lo, hi;
        asm("v_cvt_pk_bf16_f32 %0, %1, %2" : "=v"(lo) : "v"(s[kb][0]), "v"(s[kb][1]));
        asm("v_cvt_pk_bf16_f32 %0, %1, %2" : "=v"(hi) : "v"(s[kb][2]), "v"(s[kb][3]));
        int unit = kb * 2 + (lg >> 1);
        uint2 val; val.x = lo; val.y = hi;
        *(uint2*)(pbw + ((unit ^ lh7) << 4) + ((lg & 1) << 3)) = val;
      }
      bf16x8 pa0 = *(const bf16x8*)(pbw + ((lg ^ lh7) << 4));
      bf16x8 pa1 = *(const bf16x8*)(pbw + (((4 + lg) ^ lh7) << 4));
      __builtin_amdgcn_s_setprio(1);
#pragma unroll
      for (int db = 0; db < 4; ++db) {
        int row = db * 16 + lh;
        const char* rp = vbuf + row * 128;
        bf16x8 v0 = *(const bf16x8*)(rp + ((lg ^ lh7) << 4));
        bf16x8 v1 = *(const bf16x8*)(rp + (((4 + lg) ^ lh7) << 4));
        oA[db] = MFMA16(v0, pa0, oA[db]);
        oA[db] = MFMA16(v1, pa1, oA[db]);
      }
      __builtin_amdgcn_s_setprio(0);
    }
  }

  {
    float rinv = 1.0f / lsB;
    u16* ob = out + ((size_t)(b * 2048) + q0B + lh) * 1024 + h * 64;
#pragma unroll
    for (int db = 0; db < 4; ++db) {
      ushort4 pk;
      pk.x = f2bf(oB[db][0] * rinv);
      pk.y = f2bf(oB[db][1] * rinv);
      pk.z = f2bf(oB[db][2] * rinv);
      pk.w = f2bf(oB[db][3] * rinv);
      *(ushort4*)(ob + db * 16 + lg * 4) = pk;
    }
  }
  {
    float rinv = 1.0f / lsA;
    u16* ob = out + ((size_t)(b * 2048) + q0A + lh) * 1024 + h * 64;
#pragma unroll
    for (int db = 0; db < 4; ++db) {
      ushort4 pk;
      pk.x = f2bf(oA[db][0] * rinv);
      pk.y = f2bf(oA[db][1] * rinv);
      pk.z = f2bf(oA[db][2] * rinv);
      pk.w = f2bf(oA[db][3] * rinv);
      *(ushort4*)(ob + db * 16 + lg * 4) = pk;
    }
  }
}

// ---------------------------------------------------------------------------
extern "C" void kernel_launch(void* const* d_in, const int* in_sizes, int n_in,
                              void* d_out, int out_size, void* d_ws, size_t ws_size,
                              hipStream_t stream) {
  const float* x     = (const float*)d_in[0];
  const float* ln1_g = (const float*)d_in[1];
  const float* ln1_b = (const float*)d_in[2];
  const float* w_qkv = (const float*)d_in[3];
  const float* b_qkv = (const float*)d_in[4];
  const float* w_out = (const float*)d_in[5];
  const float* b_out = (const float*)d_in[6];
  const float* ln2_g = (const float*)d_in[7];
  const float* ln2_b = (const float*)d_in[8];
  const float* w1    = (const float*)d_in[9];
  const float* b1    = (const float*)d_in[10];
  const float* w2    = (const float*)d_in[11];
  const float* b2    = (const float*)d_in[12];

  char* ws = (char*)d_ws;
  // liveness-aliased layout, 142.6 MB total
  u16* wqkvT = (u16*)(ws + 0);          // 6.29 MB
  u16* woutT = (u16*)(ws + 6291456);    // 2.10 MB
  u16* w1T   = (u16*)(ws + 8388608);    // 8.39 MB
  u16* w2T   = (u16*)(ws + 16777216);   // 8.39 MB
  u16* qkv   = (u16*)(ws + 25165824);   // 50.3 MB  [b,l,3,h,d] (V region unused)
  u16* ffn1  = (u16*)(ws + 25165824);   // 67.1 MB  (aliases qkv+vt, both dead)
  u16* vtb   = (u16*)(ws + 75497472);   // 16.8 MB  [b,h,d,l] (written by QKV epi)
  u16* lnb   = (u16*)(ws + 92274688);   // 16.8 MB  (ln1 out / attn out / ln2 out)
  u16* attn  = lnb;
  float* h   = (float*)(ws + 125829120);// 33.6 MB

  // prep: 4 weight transposes (12288 blocks) + LN1 (8192 blocks), one launch
  prep_kernel<<<20480, 256, 0, stream>>>(w_qkv, wqkvT, w_out, woutT,
                                         w1, w1T, w2, w2T,
                                         x, ln1_g, ln1_b, lnb);
  // QKV: K=1024 -> ring-3 + VT_FUSE + supertile remap (nbn=24)
  gemm_ring3<0, 0, 1, 1><<<1536, 256, 0, stream>>>(lnb, wqkvT, b_qkv, nullptr, qkv, vtb, 8192, 3072, 1024);
  attn_kernel<<<1024, 256, 0, stream>>>(qkv, vtb, attn);
  // out-proj: K=1024 -> ring-3 (nbn=8: window already L2-fit, original map)
  gemm_ring3<0, 1, 0, 0><<<512, 256, 0, stream>>>(attn, woutT, b_out, x, h, nullptr, 8192, 1024, 1024);
  ln_kernel<<<8192, 256, 0, stream>>>(h, ln2_g, ln2_b, lnb);
  // FFN1: K=1024, gelu -> 2-buf + supertile remap (verified R22)
  gemm_kernel<1, 0, 1><<<2048, 256, 0, stream>>>(lnb, w1T, b1, nullptr, ffn1, 8192, 4096, 1024);
  // FFN2: K=4096 -> ring-3 counted vmcnt (long K-loop amortizes pipeline)
  gemm_ring3<0, 1, 0, 0><<<512, 256, 0, stream>>>(ffn1, w2T, b2, h, (float*)d_out, nullptr, 8192, 1024, 4096);
}